// Round 10
// baseline (1626.464 us; speedup 1.0000x reference)
//
#include <hip/hip_runtime.h>
#include <math.h>

#define CCH 48
#define SDIM 32
#define SVOL (SDIM*SDIM*SDIM)
#define NB 2

// ======== one-off weight reshape kernels ========

__global__ __launch_bounds__(256)
void reshape_tap_kernel(const float* __restrict__ w, float* __restrict__ wt,
                        int NO, int NI) {
    int i = blockIdx.x * 256 + threadIdx.x;
    int total = NO * NI * 27;
    if (i < total) {
        int tap = i / (NI * NO);
        int rem = i % (NI * NO);
        int ci = rem / NO, o = rem % NO;
        wt[i] = w[(o * NI + ci) * 27 + tap];
    }
}

__global__ __launch_bounds__(256)
void t1x1_kernel(const float* __restrict__ w, float* __restrict__ wt) {
    int i = blockIdx.x * 256 + threadIdx.x;
    if (i < CCH * CCH) { int ci = i / CCH, o = i % CCH; wt[i] = w[o * CCH + ci]; }
}

__global__ __launch_bounds__(64)
void cb_kernel(const float* __restrict__ c1w, const float* __restrict__ c1b,
               const float* __restrict__ dcb, float* __restrict__ cb) {
    int o = threadIdx.x;
    if (o < CCH) {
        float v = c1b[o];
        for (int ci = 0; ci < CCH; ci++) v += c1w[o * CCH + ci] * dcb[ci];
        cb[o] = v;
    }
}

// ---------------- LayerNorm over C ----------------
__global__ __launch_bounds__(256)
void ln_kernel(const float* __restrict__ x, const float* __restrict__ ln_s,
               const float* __restrict__ ln_b, float* __restrict__ xn) {
    int s = blockIdx.x * 256 + threadIdx.x;
    int b = blockIdx.y;
    const float* xb = x + (size_t)b * CCH * SVOL + s;
    float v[CCH];
    float mu = 0.f;
    #pragma unroll
    for (int c = 0; c < CCH; c++) { v[c] = xb[c * SVOL]; mu += v[c]; }
    mu *= (1.0f / CCH);
    float var = 0.f;
    #pragma unroll
    for (int c = 0; c < CCH; c++) { float d = v[c] - mu; var += d * d; }
    var *= (1.0f / CCH);
    float inv = rsqrtf(var + 1e-5f);
    float* o = xn + (size_t)b * CCH * SVOL + s;
    #pragma unroll
    for (int c = 0; c < CCH; c++) o[c * SVOL] = (v[c] - mu) * inv * ln_s[c] + ln_b[c];
}

// ---------------- 1x1x1 conv + exact GELU (4 groups x 12), scalar weights ----------------
__global__ __launch_bounds__(256, 4)
void p1_gelu_kernel(const float* __restrict__ xn, const float* __restrict__ wt,
                    const float* __restrict__ bias, float* __restrict__ u) {
    int tid = threadIdx.x;
    int g = blockIdx.y, b = blockIdx.z;
    int s = blockIdx.x * 256 + tid;
    const float* xb = xn + (size_t)b * CCH * SVOL + s;
    float acc[12];
    #pragma unroll
    for (int o = 0; o < 12; o++) acc[o] = bias[g * 12 + o];
    for (int c = 0; c < CCH; c++) {
        float v = xb[c * SVOL];
        const float* wr = wt + c * CCH + g * 12;
        #pragma unroll
        for (int o = 0; o < 12; o++) acc[o] += wr[o] * v;
    }
    float* ub = u + (size_t)b * CCH * SVOL + s + (size_t)(g * 12) * SVOL;
    #pragma unroll
    for (int o = 0; o < 12; o++) {
        float a = acc[o];
        ub[o * SVOL] = 0.5f * a * (1.0f + erff(a * 0.70710678118654752f));
    }
}

// ---------------- depthwise 5x5x5 pad 2, scalar weights ----------------
__global__ __launch_bounds__(256)
void dw5_kernel(const float* __restrict__ in, const float* __restrict__ w,
                const float* __restrict__ bias, float* __restrict__ out) {
    int tid = threadIdx.x;
    int c = blockIdx.y, b = blockIdx.z;
    const float* wc = w + c * 125;
    int s = blockIdx.x * 256 + tid;
    int z = s >> 10, y = (s >> 5) & 31, xx = s & 31;
    const float* ib = in + ((size_t)b * CCH + c) * SVOL;
    float acc = bias[c];
    for (int dz = -2; dz <= 2; dz++) {
        int zz = z + dz; if (zz < 0 || zz >= 32) continue;
        for (int dy = -2; dy <= 2; dy++) {
            int yy = y + dy; if (yy < 0 || yy >= 32) continue;
            #pragma unroll
            for (int dx = -2; dx <= 2; dx++) {
                int xv = xx + dx; if (xv < 0 || xv >= 32) continue;
                acc += wc[((dz + 2) * 5 + (dy + 2)) * 5 + (dx + 2)] * ib[(zz * 32 + yy) * 32 + xv];
            }
        }
    }
    out[((size_t)b * CCH + c) * SVOL + s] = acc;
}

// ---------------- depthwise 7x7x7 dil 3 pad 9, scalar weights ----------------
__global__ __launch_bounds__(256)
void dw7_kernel(const float* __restrict__ in, const float* __restrict__ w,
                const float* __restrict__ bias, float* __restrict__ out) {
    int tid = threadIdx.x;
    int c = blockIdx.y, b = blockIdx.z;
    const float* wc = w + c * 343;
    int s = blockIdx.x * 256 + tid;
    int z = s >> 10, y = (s >> 5) & 31, xx = s & 31;
    const float* ib = in + ((size_t)b * CCH + c) * SVOL;
    float acc = bias[c];
    for (int tz = 0; tz < 7; tz++) {
        int zz = z + 3 * (tz - 3); if (zz < 0 || zz >= 32) continue;
        for (int ty = 0; ty < 7; ty++) {
            int yy = y + 3 * (ty - 3); if (yy < 0 || yy >= 32) continue;
            #pragma unroll
            for (int tx = 0; tx < 7; tx++) {
                int xv = xx + 3 * (tx - 3); if (xv < 0 || xv >= 32) continue;
                acc += wc[(tz * 7 + ty) * 7 + tx] * ib[(zz * 32 + yy) * 32 + xv];
            }
        }
    }
    out[((size_t)b * CCH + c) * SVOL + s] = acc;
}

// ---------------- transpose [C][S] -> [S][C] ----------------
__global__ __launch_bounds__(256)
void transpose_kernel(const float* __restrict__ a1, float* __restrict__ a1t) {
    __shared__ float tile[CCH * 65];
    int tid = threadIdx.x;
    int b = blockIdx.y;
    int s0 = blockIdx.x * 64;
    const float* ib = a1 + (size_t)b * CCH * SVOL + s0;
    for (int i = tid; i < CCH * 64; i += 256) {
        int c = i >> 6, p = i & 63;
        tile[c * 65 + p] = ib[(size_t)c * SVOL + p];
    }
    __syncthreads();
    float* ob = a1t + ((size_t)b * SVOL + s0) * CCH;
    for (int i = tid; i < 64 * CCH; i += 256) {
        int p = i / CCH, c = i % CCH;
        ob[i] = tile[c * 65 + p];
    }
}

// ---- offset conv 3x3x3: 48->81, ci-split 2 x out-split 3, scalar weights, atomic, NO bias ----
__global__ __launch_bounds__(256, 4)
void offconv_kernel(const float* __restrict__ a1, const float* __restrict__ wt,
                    float* __restrict__ off) {
    int tid = threadIdx.x;
    int go = blockIdx.y % 3;
    int gc = blockIdx.y / 3;
    int b = blockIdx.z;
    int s = blockIdx.x * 256 + tid;
    int z = s >> 10, y = (s >> 5) & 31, xx = s & 31;
    const float* ib = a1 + ((size_t)b * CCH + gc * 24) * SVOL;
    float acc[27];
    #pragma unroll
    for (int o = 0; o < 27; o++) acc[o] = 0.f;
    for (int tap = 0; tap < 27; tap++) {
        int dz = tap / 9 - 1, dy = (tap / 3) % 3 - 1, dx = tap % 3 - 1;
        int zz = z + dz, yy = y + dy, xv = xx + dx;
        bool ok = (zz >= 0 && zz < 32 && yy >= 0 && yy < 32 && xv >= 0 && xv < 32);
        if (ok) {
            int si = (zz * 32 + yy) * 32 + xv;
            for (int cis = 0; cis < 24; cis++) {
                float v = ib[(size_t)cis * SVOL + si];
                const float* wr = wt + (size_t)(tap * CCH + gc * 24 + cis) * 81 + go * 27;
                #pragma unroll
                for (int o = 0; o < 27; o++) acc[o] += wr[o] * v;
            }
        }
    }
    float* obuf = off + (size_t)b * 81 * SVOL + (size_t)(go * 27) * SVOL + s;
    #pragma unroll
    for (int o = 0; o < 27; o++) atomicAdd(&obuf[(size_t)o * SVOL], acc[o]);
}

// ---- deformable conv 3x3x3: TAP-split 3 (9 taps each), all 48 ch, channel-last float4 gather ----
// a1t layout [b][s][48]; off bias-less; off_b added to coords here. wt layout [k][ci][48].
__global__ __launch_bounds__(256, 4)
void deform_kernel(const float* __restrict__ a1t, const float* __restrict__ off,
                   const float* __restrict__ off_b,
                   const float* __restrict__ wt, float* __restrict__ out) {
    int tid = threadIdx.x;
    int gt = blockIdx.y;            // tap group 0..2
    int b = blockIdx.z;
    int s = blockIdx.x * 256 + tid;
    int z = s >> 10, y = (s >> 5) & 31, xx = s & 31;
    const float4* ibase = (const float4*)(a1t + (size_t)b * SVOL * CCH);
    const float* ob = off + (size_t)b * 81 * SVOL + s;
    float acc[CCH];
    #pragma unroll
    for (int o = 0; o < CCH; o++) acc[o] = 0.f;
    for (int kk = 0; kk < 9; kk++) {
        int k = gt * 9 + kk;
        int kd = k / 9 - 1, kh = (k / 3) % 3 - 1, kw = k % 3 - 1;
        float zf = (float)(z + kd) + ob[(size_t)(k * 3 + 0) * SVOL] + off_b[k * 3 + 0];
        float yf = (float)(y + kh) + ob[(size_t)(k * 3 + 1) * SVOL] + off_b[k * 3 + 1];
        float xf = (float)(xx + kw) + ob[(size_t)(k * 3 + 2) * SVOL] + off_b[k * 3 + 2];
        float z0 = floorf(zf), y0 = floorf(yf), x0 = floorf(xf);
        float tz = zf - z0, ty = yf - y0, tx = xf - x0;
        int iz0 = (int)z0, iy0 = (int)y0, ix0 = (int)x0;
        float cw[8]; int cidx[8];
        #pragma unroll
        for (int corner = 0; corner < 8; corner++) {
            int dz = corner >> 2, dy = (corner >> 1) & 1, dx = corner & 1;
            int zi = iz0 + dz, yi = iy0 + dy, xi = ix0 + dx;
            bool valid = (zi >= 0 && zi < 32 && yi >= 0 && yi < 32 && xi >= 0 && xi < 32);
            float wgt = (dz ? tz : 1.f - tz) * (dy ? ty : 1.f - ty) * (dx ? tx : 1.f - tx);
            cw[corner] = valid ? wgt : 0.f;
            int zc = min(max(zi, 0), 31), yc = min(max(yi, 0), 31), xc = min(max(xi, 0), 31);
            cidx[corner] = (zc * 32 + yc) * 32 + xc;
        }
        // half 0: channels 0..23
        {
            float val[24];
            #pragma unroll
            for (int j = 0; j < 24; j++) val[j] = 0.f;
            #pragma unroll
            for (int corner = 0; corner < 8; corner++) {
                float cwv = cw[corner];
                const float4* p4 = ibase + (size_t)cidx[corner] * 12;
                #pragma unroll
                for (int j = 0; j < 6; j++) {
                    float4 v = p4[j];
                    val[4 * j + 0] += cwv * v.x; val[4 * j + 1] += cwv * v.y;
                    val[4 * j + 2] += cwv * v.z; val[4 * j + 3] += cwv * v.w;
                }
            }
            #pragma unroll
            for (int ci = 0; ci < 24; ci++) {
                float v = val[ci];
                const float* wr = wt + (size_t)(k * CCH + ci) * CCH;   // uniform
                #pragma unroll
                for (int o = 0; o < CCH; o++) acc[o] += wr[o] * v;
            }
        }
        // half 1: channels 24..47
        {
            float val[24];
            #pragma unroll
            for (int j = 0; j < 24; j++) val[j] = 0.f;
            #pragma unroll
            for (int corner = 0; corner < 8; corner++) {
                float cwv = cw[corner];
                const float4* p4 = ibase + (size_t)cidx[corner] * 12 + 6;
                #pragma unroll
                for (int j = 0; j < 6; j++) {
                    float4 v = p4[j];
                    val[4 * j + 0] += cwv * v.x; val[4 * j + 1] += cwv * v.y;
                    val[4 * j + 2] += cwv * v.z; val[4 * j + 3] += cwv * v.w;
                }
            }
            #pragma unroll
            for (int ci = 0; ci < 24; ci++) {
                float v = val[ci];
                const float* wr = wt + (size_t)(k * CCH + 24 + ci) * CCH;   // uniform
                #pragma unroll
                for (int o = 0; o < CCH; o++) acc[o] += wr[o] * v;
            }
        }
    }
    float* op = out + (size_t)b * CCH * SVOL + s;
    #pragma unroll
    for (int o = 0; o < CCH; o++) atomicAdd(&op[(size_t)o * SVOL], acc[o]);
}

// ---- gate1: a2 = (c1 . dc + cb) * u   (4 groups x 12), scalar weights ----
__global__ __launch_bounds__(256, 4)
void gate1_kernel(const float* __restrict__ dc, const float* __restrict__ u,
                  const float* __restrict__ wt, const float* __restrict__ cb,
                  float* __restrict__ a2buf) {
    int tid = threadIdx.x;
    int g = blockIdx.y, b = blockIdx.z;
    int s = blockIdx.x * 256 + tid;
    size_t base = (size_t)b * CCH * SVOL + s;
    float acc[12];
    #pragma unroll
    for (int o = 0; o < 12; o++) acc[o] = cb[g * 12 + o];
    for (int ci = 0; ci < CCH; ci++) {
        float v = dc[base + (size_t)ci * SVOL];
        const float* wr = wt + ci * CCH + g * 12;
        #pragma unroll
        for (int o = 0; o < 12; o++) acc[o] += wr[o] * v;
    }
    #pragma unroll
    for (int o = 0; o < 12; o++) {
        size_t oo = base + (size_t)(g * 12 + o) * SVOL;
        a2buf[oo] = acc[o] * u[oo];
    }
}

// ---- gate2: skip = x + gamma*(p2 . a2 + p2b + xn)  (4 groups x 12), scalar weights ----
__global__ __launch_bounds__(256, 4)
void gate2_kernel(const float* __restrict__ a2buf, const float* __restrict__ xn,
                  const float* __restrict__ x,
                  const float* __restrict__ wt, const float* __restrict__ p2b,
                  const float* __restrict__ gamma, float* __restrict__ skip) {
    int tid = threadIdx.x;
    int g = blockIdx.y, b = blockIdx.z;
    int s = blockIdx.x * 256 + tid;
    size_t base = (size_t)b * CCH * SVOL + s;
    float acc[12];
    #pragma unroll
    for (int o = 0; o < 12; o++) acc[o] = p2b[g * 12 + o];
    for (int ci = 0; ci < CCH; ci++) {
        float v = a2buf[base + (size_t)ci * SVOL];
        const float* wr = wt + ci * CCH + g * 12;
        #pragma unroll
        for (int o = 0; o < 12; o++) acc[o] += wr[o] * v;
    }
    #pragma unroll
    for (int o = 0; o < 12; o++) {
        int oc = g * 12 + o;
        float vv = acc[o] + xn[base + (size_t)oc * SVOL];
        skip[base + (size_t)oc * SVOL] = x[base + (size_t)oc * SVOL] + gamma[oc] * vv;
    }
}

// ---- u1: 3x3x3 conv + BN1 + LeakyReLU (4 groups x 12), scalar weights [tap][ci][48] ----
__global__ __launch_bounds__(256, 4)
void u1_kernel(const float* __restrict__ in, const float* __restrict__ wt,
               const float* __restrict__ bs, const float* __restrict__ bb,
               const float* __restrict__ bm, const float* __restrict__ bv,
               float* __restrict__ out) {
    int tid = threadIdx.x;
    int g = blockIdx.y, b = blockIdx.z;
    int s = blockIdx.x * 256 + tid;
    int z = s >> 10, y = (s >> 5) & 31, xx = s & 31;
    const float* ib = in + (size_t)b * CCH * SVOL;
    float acc[12];
    #pragma unroll
    for (int o = 0; o < 12; o++) acc[o] = 0.f;
    for (int tap = 0; tap < 27; tap++) {
        int dz = tap / 9 - 1, dy = (tap / 3) % 3 - 1, dx = tap % 3 - 1;
        int zz = z + dz, yy = y + dy, xv = xx + dx;
        bool ok = (zz >= 0 && zz < 32 && yy >= 0 && yy < 32 && xv >= 0 && xv < 32);
        if (ok) {
            int si = (zz * 32 + yy) * 32 + xv;
            for (int ci = 0; ci < CCH; ci++) {
                float v = ib[(size_t)ci * SVOL + si];
                const float* wr = wt + (size_t)(tap * CCH + ci) * CCH + g * 12;
                #pragma unroll
                for (int o = 0; o < 12; o++) acc[o] += wr[o] * v;
            }
        }
    }
    float* op = out + (size_t)b * CCH * SVOL + (size_t)(g * 12) * SVOL + s;
    #pragma unroll
    for (int o = 0; o < 12; o++) {
        int oc = g * 12 + o;
        float inv = rsqrtf(bv[oc] + 1e-5f);
        float h = (acc[o] - bm[oc]) * (bs[oc] * inv) + bb[oc];
        op[(size_t)o * SVOL] = h >= 0.f ? h : 0.01f * h;
    }
}

// ---- u2_bn: 3x3x3 conv + BN2 + (+skip) + LeakyReLU -> attn (4 groups x 12), scalar weights ----
__global__ __launch_bounds__(256, 4)
void u2_bn_kernel(const float* __restrict__ h1, const float* __restrict__ skip,
                  const float* __restrict__ wt,
                  const float* __restrict__ bs, const float* __restrict__ bb,
                  const float* __restrict__ bm, const float* __restrict__ bv,
                  float* __restrict__ attn) {
    int tid = threadIdx.x;
    int g = blockIdx.y, b = blockIdx.z;
    int s = blockIdx.x * 256 + tid;
    int z = s >> 10, y = (s >> 5) & 31, xx = s & 31;
    const float* ib = h1 + (size_t)b * CCH * SVOL;
    float acc[12];
    #pragma unroll
    for (int o = 0; o < 12; o++) acc[o] = 0.f;
    for (int tap = 0; tap < 27; tap++) {
        int dz = tap / 9 - 1, dy = (tap / 3) % 3 - 1, dx = tap % 3 - 1;
        int zz = z + dz, yy = y + dy, xv = xx + dx;
        bool ok = (zz >= 0 && zz < 32 && yy >= 0 && yy < 32 && xv >= 0 && xv < 32);
        if (ok) {
            int si = (zz * 32 + yy) * 32 + xv;
            for (int ci = 0; ci < CCH; ci++) {
                float v = ib[(size_t)ci * SVOL + si];
                const float* wr = wt + (size_t)(tap * CCH + ci) * CCH + g * 12;
                #pragma unroll
                for (int o = 0; o < 12; o++) acc[o] += wr[o] * v;
            }
        }
    }
    size_t base = (size_t)b * CCH * SVOL + s;
    #pragma unroll
    for (int o = 0; o < 12; o++) {
        int oc = g * 12 + o;
        float inv = rsqrtf(bv[oc] + 1e-5f);
        float h = (acc[o] - bm[oc]) * (bs[oc] * inv) + bb[oc];
        float a = h + skip[base + (size_t)oc * SVOL];
        attn[base + (size_t)oc * SVOL] = a >= 0.f ? a : 0.01f * a;
    }
}

// ---- pr_final: out = skip + pr(attn)  (4 groups x 12), scalar weights ----
__global__ __launch_bounds__(256, 4)
void pr_final_kernel(const float* __restrict__ attn, const float* __restrict__ skip,
                     const float* __restrict__ wt, const float* __restrict__ prb,
                     float* __restrict__ out) {
    int tid = threadIdx.x;
    int g = blockIdx.y, b = blockIdx.z;
    int s = blockIdx.x * 256 + tid;
    size_t base = (size_t)b * CCH * SVOL + s;
    float acc[12];
    #pragma unroll
    for (int o = 0; o < 12; o++) acc[o] = prb[g * 12 + o];
    for (int ci = 0; ci < CCH; ci++) {
        float v = attn[base + (size_t)ci * SVOL];
        const float* wr = wt + ci * CCH + g * 12;
        #pragma unroll
        for (int o = 0; o < 12; o++) acc[o] += wr[o] * v;
    }
    #pragma unroll
    for (int o = 0; o < 12; o++) {
        int oc = g * 12 + o;
        out[base + (size_t)oc * SVOL] = skip[base + (size_t)oc * SVOL] + acc[o];
    }
}

extern "C" void kernel_launch(void* const* d_in, const int* in_sizes, int n_in,
                              void* d_out, int out_size, void* d_ws, size_t ws_size,
                              hipStream_t stream) {
    (void)in_sizes; (void)n_in; (void)out_size; (void)ws_size;
    const float* x     = (const float*)d_in[0];
    const float* ln_s  = (const float*)d_in[1];
    const float* ln_b  = (const float*)d_in[2];
    const float* gamma = (const float*)d_in[3];
    const float* p1_w  = (const float*)d_in[4];
    const float* p1_b  = (const float*)d_in[5];
    const float* p2_w  = (const float*)d_in[6];
    const float* p2_b  = (const float*)d_in[7];
    const float* c0_w  = (const float*)d_in[8];
    const float* c0_b  = (const float*)d_in[9];
    const float* cs_w  = (const float*)d_in[10];
    const float* cs_b  = (const float*)d_in[11];
    const float* off_w = (const float*)d_in[12];
    const float* off_b = (const float*)d_in[13];
    const float* dc_w  = (const float*)d_in[14];
    const float* dc_b  = (const float*)d_in[15];
    const float* c1_w  = (const float*)d_in[16];
    const float* c1_b  = (const float*)d_in[17];
    const float* u1_w  = (const float*)d_in[18];
    const float* bn1_s = (const float*)d_in[19];
    const float* bn1_b = (const float*)d_in[20];
    const float* bn1_m = (const float*)d_in[21];
    const float* bn1_v = (const float*)d_in[22];
    const float* u2_w  = (const float*)d_in[23];
    const float* bn2_s = (const float*)d_in[24];
    const float* bn2_b = (const float*)d_in[25];
    const float* bn2_m = (const float*)d_in[26];
    const float* bn2_v = (const float*)d_in[27];
    const float* pr_w  = (const float*)d_in[28];
    const float* pr_b  = (const float*)d_in[29];
    float* out = (float*)d_out;

    float* wsf = (float*)d_ws;
    const size_t TS = (size_t)NB * CCH * SVOL;   // 3,145,728 floats
    float* xn   = out;            // d_out doubles as xn (dead before final write)
    float* ubuf = wsf;            // u (gelu out) -> h1 (u1 out)
    float* bufA = wsf + TS;       // dw5 out -> a1t (ch-last) -> skip
    float* bufB = wsf + 2 * TS;   // dw7 out (a1) -> deform partials (dc)
    float* offb = wsf + 3 * TS;   // offset partials [B,81,S] -> a2 -> attn
    float* wtb    = wsf + 3 * TS + (size_t)NB * 81 * SVOL;
    float* wt_off = wtb;                    // 27*48*81 = 104976
    float* wt_dc  = wt_off + 104976;        // 27*48*48 = 62208
    float* wt_u1  = wt_dc + 62208;
    float* wt_u2  = wt_u1 + 62208;
    float* pt_p1  = wt_u2 + 62208;          // 2304
    float* pt_c1  = pt_p1 + 2304;
    float* pt_p2  = pt_c1 + 2304;
    float* pt_pr  = pt_p2 + 2304;
    float* cb_all = pt_pr + 2304;           // 48

    dim3 blk(256);
    dim3 gpos(SVOL / 256, NB);
    dim3 g4(SVOL / 256, 4, NB);
    dim3 g6(SVOL / 256, 6, NB);
    dim3 gdef(SVOL / 256, 3, NB);
    dim3 gdw(SVOL / 256, CCH, NB);
    dim3 gtr(SVOL / 64, NB);

    hipLaunchKernelGGL(reshape_tap_kernel, dim3((104976 + 255) / 256), blk, 0, stream, off_w, wt_off, 81, CCH);
    hipLaunchKernelGGL(reshape_tap_kernel, dim3((62208 + 255) / 256),  blk, 0, stream, dc_w,  wt_dc,  CCH, CCH);
    hipLaunchKernelGGL(reshape_tap_kernel, dim3((62208 + 255) / 256),  blk, 0, stream, u1_w,  wt_u1,  CCH, CCH);
    hipLaunchKernelGGL(reshape_tap_kernel, dim3((62208 + 255) / 256),  blk, 0, stream, u2_w,  wt_u2,  CCH, CCH);
    hipLaunchKernelGGL(t1x1_kernel, dim3(9), blk, 0, stream, p1_w, pt_p1);
    hipLaunchKernelGGL(t1x1_kernel, dim3(9), blk, 0, stream, c1_w, pt_c1);
    hipLaunchKernelGGL(t1x1_kernel, dim3(9), blk, 0, stream, p2_w, pt_p2);
    hipLaunchKernelGGL(t1x1_kernel, dim3(9), blk, 0, stream, pr_w, pt_pr);
    hipLaunchKernelGGL(cb_kernel, dim3(1), dim3(64), 0, stream, c1_w, c1_b, dc_b, cb_all);

    hipLaunchKernelGGL(ln_kernel,        gpos, blk, 0, stream, x, ln_s, ln_b, xn);
    hipLaunchKernelGGL(p1_gelu_kernel,   g4,   blk, 0, stream, xn, pt_p1, p1_b, ubuf);
    hipLaunchKernelGGL(dw5_kernel,       gdw,  blk, 0, stream, ubuf, c0_w, c0_b, bufA);
    hipLaunchKernelGGL(dw7_kernel,       gdw,  blk, 0, stream, bufA, cs_w, cs_b, bufB);
    hipLaunchKernelGGL(transpose_kernel, gtr,  blk, 0, stream, bufB, bufA);   // a1 -> a1t
    hipMemsetAsync(offb, 0, (size_t)NB * 81 * SVOL * sizeof(float), stream);
    hipLaunchKernelGGL(offconv_kernel,   g6,   blk, 0, stream, bufB, wt_off, offb);
    hipMemsetAsync(bufB, 0, TS * sizeof(float), stream);
    hipLaunchKernelGGL(deform_kernel,    gdef, blk, 0, stream, bufA, offb, off_b, wt_dc, bufB);
    hipLaunchKernelGGL(gate1_kernel,     g4,   blk, 0, stream, bufB, ubuf, pt_c1, cb_all, offb);
    hipLaunchKernelGGL(gate2_kernel,     g4,   blk, 0, stream, offb, xn, x, pt_p2, p2_b, gamma, bufA);
    hipLaunchKernelGGL(u1_kernel,        g4,   blk, 0, stream, bufA, wt_u1,
                       bn1_s, bn1_b, bn1_m, bn1_v, ubuf);
    hipLaunchKernelGGL(u2_bn_kernel,     g4,   blk, 0, stream, ubuf, bufA, wt_u2,
                       bn2_s, bn2_b, bn2_m, bn2_v, offb);
    hipLaunchKernelGGL(pr_final_kernel,  g4,   blk, 0, stream, offb, bufA, pt_pr, pr_b, out);
}

// Round 11
// 1145.895 us; speedup vs baseline: 1.4194x; 1.4194x over previous
//
#include <hip/hip_runtime.h>
#include <hip/hip_fp16.h>
#include <math.h>

#define CCH 48
#define SDIM 32
#define SVOL (SDIM*SDIM*SDIM)
#define NB 2

// ======== one-off weight reshape kernels ========

__global__ __launch_bounds__(256)
void reshape_tap_kernel(const float* __restrict__ w, float* __restrict__ wt,
                        int NO, int NI) {
    int i = blockIdx.x * 256 + threadIdx.x;
    int total = NO * NI * 27;
    if (i < total) {
        int tap = i / (NI * NO);
        int rem = i % (NI * NO);
        int ci = rem / NO, o = rem % NO;
        wt[i] = w[(o * NI + ci) * 27 + tap];
    }
}

__global__ __launch_bounds__(256)
void t1x1_kernel(const float* __restrict__ w, float* __restrict__ wt) {
    int i = blockIdx.x * 256 + threadIdx.x;
    if (i < CCH * CCH) { int ci = i / CCH, o = i % CCH; wt[i] = w[o * CCH + ci]; }
}

__global__ __launch_bounds__(64)
void cb_kernel(const float* __restrict__ c1w, const float* __restrict__ c1b,
               const float* __restrict__ dcb, float* __restrict__ cb) {
    int o = threadIdx.x;
    if (o < CCH) {
        float v = c1b[o];
        for (int ci = 0; ci < CCH; ci++) v += c1w[o * CCH + ci] * dcb[ci];
        cb[o] = v;
    }
}

// ---------------- LayerNorm over C ----------------
__global__ __launch_bounds__(256)
void ln_kernel(const float* __restrict__ x, const float* __restrict__ ln_s,
               const float* __restrict__ ln_b, float* __restrict__ xn) {
    int s = blockIdx.x * 256 + threadIdx.x;
    int b = blockIdx.y;
    const float* xb = x + (size_t)b * CCH * SVOL + s;
    float v[CCH];
    float mu = 0.f;
    #pragma unroll
    for (int c = 0; c < CCH; c++) { v[c] = xb[c * SVOL]; mu += v[c]; }
    mu *= (1.0f / CCH);
    float var = 0.f;
    #pragma unroll
    for (int c = 0; c < CCH; c++) { float d = v[c] - mu; var += d * d; }
    var *= (1.0f / CCH);
    float inv = rsqrtf(var + 1e-5f);
    float* o = xn + (size_t)b * CCH * SVOL + s;
    #pragma unroll
    for (int c = 0; c < CCH; c++) o[c * SVOL] = (v[c] - mu) * inv * ln_s[c] + ln_b[c];
}

// ---------------- 1x1x1 conv + exact GELU (4 groups x 12), scalar weights ----------------
__global__ __launch_bounds__(256, 4)
void p1_gelu_kernel(const float* __restrict__ xn, const float* __restrict__ wt,
                    const float* __restrict__ bias, float* __restrict__ u) {
    int tid = threadIdx.x;
    int g = blockIdx.y, b = blockIdx.z;
    int s = blockIdx.x * 256 + tid;
    const float* xb = xn + (size_t)b * CCH * SVOL + s;
    float acc[12];
    #pragma unroll
    for (int o = 0; o < 12; o++) acc[o] = bias[g * 12 + o];
    for (int c = 0; c < CCH; c++) {
        float v = xb[c * SVOL];
        const float* wr = wt + c * CCH + g * 12;
        #pragma unroll
        for (int o = 0; o < 12; o++) acc[o] += wr[o] * v;
    }
    float* ub = u + (size_t)b * CCH * SVOL + s + (size_t)(g * 12) * SVOL;
    #pragma unroll
    for (int o = 0; o < 12; o++) {
        float a = acc[o];
        ub[o * SVOL] = 0.5f * a * (1.0f + erff(a * 0.70710678118654752f));
    }
}

// ---------------- depthwise 5x5x5 pad 2, scalar weights ----------------
__global__ __launch_bounds__(256)
void dw5_kernel(const float* __restrict__ in, const float* __restrict__ w,
                const float* __restrict__ bias, float* __restrict__ out) {
    int tid = threadIdx.x;
    int c = blockIdx.y, b = blockIdx.z;
    const float* wc = w + c * 125;
    int s = blockIdx.x * 256 + tid;
    int z = s >> 10, y = (s >> 5) & 31, xx = s & 31;
    const float* ib = in + ((size_t)b * CCH + c) * SVOL;
    float acc = bias[c];
    for (int dz = -2; dz <= 2; dz++) {
        int zz = z + dz; if (zz < 0 || zz >= 32) continue;
        for (int dy = -2; dy <= 2; dy++) {
            int yy = y + dy; if (yy < 0 || yy >= 32) continue;
            #pragma unroll
            for (int dx = -2; dx <= 2; dx++) {
                int xv = xx + dx; if (xv < 0 || xv >= 32) continue;
                acc += wc[((dz + 2) * 5 + (dy + 2)) * 5 + (dx + 2)] * ib[(zz * 32 + yy) * 32 + xv];
            }
        }
    }
    out[((size_t)b * CCH + c) * SVOL + s] = acc;
}

// ---------------- depthwise 7x7x7 dil 3 pad 9, scalar weights ----------------
__global__ __launch_bounds__(256)
void dw7_kernel(const float* __restrict__ in, const float* __restrict__ w,
                const float* __restrict__ bias, float* __restrict__ out) {
    int tid = threadIdx.x;
    int c = blockIdx.y, b = blockIdx.z;
    const float* wc = w + c * 343;
    int s = blockIdx.x * 256 + tid;
    int z = s >> 10, y = (s >> 5) & 31, xx = s & 31;
    const float* ib = in + ((size_t)b * CCH + c) * SVOL;
    float acc = bias[c];
    for (int tz = 0; tz < 7; tz++) {
        int zz = z + 3 * (tz - 3); if (zz < 0 || zz >= 32) continue;
        for (int ty = 0; ty < 7; ty++) {
            int yy = y + 3 * (ty - 3); if (yy < 0 || yy >= 32) continue;
            #pragma unroll
            for (int tx = 0; tx < 7; tx++) {
                int xv = xx + 3 * (tx - 3); if (xv < 0 || xv >= 32) continue;
                acc += wc[(tz * 7 + ty) * 7 + tx] * ib[(zz * 32 + yy) * 32 + xv];
            }
        }
    }
    out[((size_t)b * CCH + c) * SVOL + s] = acc;
}

// ---------------- transpose [C][S] -> [S][C] fp16 records ----------------
__global__ __launch_bounds__(256)
void transpose_h_kernel(const float* __restrict__ a1, __half* __restrict__ a1h) {
    __shared__ float tile[CCH * 65];
    int tid = threadIdx.x;
    int b = blockIdx.y;
    int s0 = blockIdx.x * 64;
    const float* ib = a1 + (size_t)b * CCH * SVOL + s0;
    for (int i = tid; i < CCH * 64; i += 256) {
        int c = i >> 6, p = i & 63;
        tile[c * 65 + p] = ib[(size_t)c * SVOL + p];
    }
    __syncthreads();
    __half* ob = a1h + ((size_t)b * SVOL + s0) * CCH;
    for (int i = tid; i < 64 * CCH; i += 256) {
        int p = i / CCH, c = i % CCH;
        ob[i] = __float2half(tile[c * 65 + p]);
    }
}

// ---- offset conv 3x3x3: 48->81, ci-split 2 x out-split 3, scalar weights, atomic, NO bias ----
__global__ __launch_bounds__(256, 4)
void offconv_kernel(const float* __restrict__ a1, const float* __restrict__ wt,
                    float* __restrict__ off) {
    int tid = threadIdx.x;
    int go = blockIdx.y % 3;
    int gc = blockIdx.y / 3;
    int b = blockIdx.z;
    int s = blockIdx.x * 256 + tid;
    int z = s >> 10, y = (s >> 5) & 31, xx = s & 31;
    const float* ib = a1 + ((size_t)b * CCH + gc * 24) * SVOL;
    float acc[27];
    #pragma unroll
    for (int o = 0; o < 27; o++) acc[o] = 0.f;
    for (int tap = 0; tap < 27; tap++) {
        int dz = tap / 9 - 1, dy = (tap / 3) % 3 - 1, dx = tap % 3 - 1;
        int zz = z + dz, yy = y + dy, xv = xx + dx;
        bool ok = (zz >= 0 && zz < 32 && yy >= 0 && yy < 32 && xv >= 0 && xv < 32);
        if (ok) {
            int si = (zz * 32 + yy) * 32 + xv;
            for (int cis = 0; cis < 24; cis++) {
                float v = ib[(size_t)cis * SVOL + si];
                const float* wr = wt + (size_t)(tap * CCH + gc * 24 + cis) * 81 + go * 27;
                #pragma unroll
                for (int o = 0; o < 27; o++) acc[o] += wr[o] * v;
            }
        }
    }
    float* obuf = off + (size_t)b * 81 * SVOL + (size_t)(go * 27) * SVOL + s;
    #pragma unroll
    for (int o = 0; o < 27; o++) atomicAdd(&obuf[(size_t)o * SVOL], acc[o]);
}

// ---- deformable conv 3x3x3: ci-split 3 (16 ch), fp16 channel-last gather (2x16B/corner) ----
// a1h layout [b][s][48] half; off bias-less; off_b added to coords here. wt layout [k][ci][48].
struct h8 { __half2 a, b, c, d; };   // 16 bytes = 8 halves

__global__ __launch_bounds__(256, 4)
void deform_kernel(const __half* __restrict__ a1h, const float* __restrict__ off,
                   const float* __restrict__ off_b,
                   const float* __restrict__ wt, float* __restrict__ out) {
    int tid = threadIdx.x;
    int gc = blockIdx.y;            // ci group 0..2 (16 ch each)
    int b = blockIdx.z;
    int s = blockIdx.x * 256 + tid;
    int z = s >> 10, y = (s >> 5) & 31, xx = s & 31;
    const __half* abase = a1h + (size_t)b * SVOL * CCH + gc * 16;
    const float* ob = off + (size_t)b * 81 * SVOL + s;
    float acc[CCH];
    #pragma unroll
    for (int o = 0; o < CCH; o++) acc[o] = 0.f;
    for (int k = 0; k < 27; k++) {
        int kd = k / 9 - 1, kh = (k / 3) % 3 - 1, kw = k % 3 - 1;
        float zf = (float)(z + kd) + ob[(size_t)(k * 3 + 0) * SVOL] + off_b[k * 3 + 0];
        float yf = (float)(y + kh) + ob[(size_t)(k * 3 + 1) * SVOL] + off_b[k * 3 + 1];
        float xf = (float)(xx + kw) + ob[(size_t)(k * 3 + 2) * SVOL] + off_b[k * 3 + 2];
        float z0 = floorf(zf), y0 = floorf(yf), x0 = floorf(xf);
        float tz = zf - z0, ty = yf - y0, tx = xf - x0;
        int iz0 = (int)z0, iy0 = (int)y0, ix0 = (int)x0;
        float val[16];
        #pragma unroll
        for (int j = 0; j < 16; j++) val[j] = 0.f;
        #pragma unroll
        for (int corner = 0; corner < 8; corner++) {
            int dz = corner >> 2, dy = (corner >> 1) & 1, dx = corner & 1;
            int zi = iz0 + dz, yi = iy0 + dy, xi = ix0 + dx;
            bool valid = (zi >= 0 && zi < 32 && yi >= 0 && yi < 32 && xi >= 0 && xi < 32);
            float wgt = (dz ? tz : 1.f - tz) * (dy ? ty : 1.f - ty) * (dx ? tx : 1.f - tx);
            float cwv = valid ? wgt : 0.f;
            int zc = min(max(zi, 0), 31), yc = min(max(yi, 0), 31), xc = min(max(xi, 0), 31);
            int cidx = (zc * 32 + yc) * 32 + xc;
            const h8* pv = (const h8*)(abase + (size_t)cidx * CCH);
            h8 q0 = pv[0], q1 = pv[1];
            float2 f;
            f = __half22float2(q0.a); val[0]  += cwv * f.x; val[1]  += cwv * f.y;
            f = __half22float2(q0.b); val[2]  += cwv * f.x; val[3]  += cwv * f.y;
            f = __half22float2(q0.c); val[4]  += cwv * f.x; val[5]  += cwv * f.y;
            f = __half22float2(q0.d); val[6]  += cwv * f.x; val[7]  += cwv * f.y;
            f = __half22float2(q1.a); val[8]  += cwv * f.x; val[9]  += cwv * f.y;
            f = __half22float2(q1.b); val[10] += cwv * f.x; val[11] += cwv * f.y;
            f = __half22float2(q1.c); val[12] += cwv * f.x; val[13] += cwv * f.y;
            f = __half22float2(q1.d); val[14] += cwv * f.x; val[15] += cwv * f.y;
        }
        #pragma unroll
        for (int cis = 0; cis < 16; cis++) {
            float v = val[cis];
            const float* wr = wt + (size_t)(k * CCH + gc * 16 + cis) * CCH;   // uniform
            #pragma unroll
            for (int o = 0; o < CCH; o++) acc[o] += wr[o] * v;
        }
    }
    float* op = out + (size_t)b * CCH * SVOL + s;
    #pragma unroll
    for (int o = 0; o < CCH; o++) atomicAdd(&op[(size_t)o * SVOL], acc[o]);
}

// ---- gate1: a2 = (c1 . dc + cb) * u   (4 groups x 12), scalar weights ----
__global__ __launch_bounds__(256, 4)
void gate1_kernel(const float* __restrict__ dc, const float* __restrict__ u,
                  const float* __restrict__ wt, const float* __restrict__ cb,
                  float* __restrict__ a2buf) {
    int tid = threadIdx.x;
    int g = blockIdx.y, b = blockIdx.z;
    int s = blockIdx.x * 256 + tid;
    size_t base = (size_t)b * CCH * SVOL + s;
    float acc[12];
    #pragma unroll
    for (int o = 0; o < 12; o++) acc[o] = cb[g * 12 + o];
    for (int ci = 0; ci < CCH; ci++) {
        float v = dc[base + (size_t)ci * SVOL];
        const float* wr = wt + ci * CCH + g * 12;
        #pragma unroll
        for (int o = 0; o < 12; o++) acc[o] += wr[o] * v;
    }
    #pragma unroll
    for (int o = 0; o < 12; o++) {
        size_t oo = base + (size_t)(g * 12 + o) * SVOL;
        a2buf[oo] = acc[o] * u[oo];
    }
}

// ---- gate2: skip = x + gamma*(p2 . a2 + p2b + xn)  (4 groups x 12), scalar weights ----
__global__ __launch_bounds__(256, 4)
void gate2_kernel(const float* __restrict__ a2buf, const float* __restrict__ xn,
                  const float* __restrict__ x,
                  const float* __restrict__ wt, const float* __restrict__ p2b,
                  const float* __restrict__ gamma, float* __restrict__ skip) {
    int tid = threadIdx.x;
    int g = blockIdx.y, b = blockIdx.z;
    int s = blockIdx.x * 256 + tid;
    size_t base = (size_t)b * CCH * SVOL + s;
    float acc[12];
    #pragma unroll
    for (int o = 0; o < 12; o++) acc[o] = p2b[g * 12 + o];
    for (int ci = 0; ci < CCH; ci++) {
        float v = a2buf[base + (size_t)ci * SVOL];
        const float* wr = wt + ci * CCH + g * 12;
        #pragma unroll
        for (int o = 0; o < 12; o++) acc[o] += wr[o] * v;
    }
    #pragma unroll
    for (int o = 0; o < 12; o++) {
        int oc = g * 12 + o;
        float vv = acc[o] + xn[base + (size_t)oc * SVOL];
        skip[base + (size_t)oc * SVOL] = x[base + (size_t)oc * SVOL] + gamma[oc] * vv;
    }
}

// ---- u1: 3x3x3 conv + BN1 + LeakyReLU (4 groups x 12), scalar weights [tap][ci][48] ----
__global__ __launch_bounds__(256, 4)
void u1_kernel(const float* __restrict__ in, const float* __restrict__ wt,
               const float* __restrict__ bs, const float* __restrict__ bb,
               const float* __restrict__ bm, const float* __restrict__ bv,
               float* __restrict__ out) {
    int tid = threadIdx.x;
    int g = blockIdx.y, b = blockIdx.z;
    int s = blockIdx.x * 256 + tid;
    int z = s >> 10, y = (s >> 5) & 31, xx = s & 31;
    const float* ib = in + (size_t)b * CCH * SVOL;
    float acc[12];
    #pragma unroll
    for (int o = 0; o < 12; o++) acc[o] = 0.f;
    for (int tap = 0; tap < 27; tap++) {
        int dz = tap / 9 - 1, dy = (tap / 3) % 3 - 1, dx = tap % 3 - 1;
        int zz = z + dz, yy = y + dy, xv = xx + dx;
        bool ok = (zz >= 0 && zz < 32 && yy >= 0 && yy < 32 && xv >= 0 && xv < 32);
        if (ok) {
            int si = (zz * 32 + yy) * 32 + xv;
            for (int ci = 0; ci < CCH; ci++) {
                float v = ib[(size_t)ci * SVOL + si];
                const float* wr = wt + (size_t)(tap * CCH + ci) * CCH + g * 12;
                #pragma unroll
                for (int o = 0; o < 12; o++) acc[o] += wr[o] * v;
            }
        }
    }
    float* op = out + (size_t)b * CCH * SVOL + (size_t)(g * 12) * SVOL + s;
    #pragma unroll
    for (int o = 0; o < 12; o++) {
        int oc = g * 12 + o;
        float inv = rsqrtf(bv[oc] + 1e-5f);
        float h = (acc[o] - bm[oc]) * (bs[oc] * inv) + bb[oc];
        op[(size_t)o * SVOL] = h >= 0.f ? h : 0.01f * h;
    }
}

// ---- u2_bn: 3x3x3 conv + BN2 + (+skip) + LeakyReLU -> attn (4 groups x 12), scalar weights ----
__global__ __launch_bounds__(256, 4)
void u2_bn_kernel(const float* __restrict__ h1, const float* __restrict__ skip,
                  const float* __restrict__ wt,
                  const float* __restrict__ bs, const float* __restrict__ bb,
                  const float* __restrict__ bm, const float* __restrict__ bv,
                  float* __restrict__ attn) {
    int tid = threadIdx.x;
    int g = blockIdx.y, b = blockIdx.z;
    int s = blockIdx.x * 256 + tid;
    int z = s >> 10, y = (s >> 5) & 31, xx = s & 31;
    const float* ib = h1 + (size_t)b * CCH * SVOL;
    float acc[12];
    #pragma unroll
    for (int o = 0; o < 12; o++) acc[o] = 0.f;
    for (int tap = 0; tap < 27; tap++) {
        int dz = tap / 9 - 1, dy = (tap / 3) % 3 - 1, dx = tap % 3 - 1;
        int zz = z + dz, yy = y + dy, xv = xx + dx;
        bool ok = (zz >= 0 && zz < 32 && yy >= 0 && yy < 32 && xv >= 0 && xv < 32);
        if (ok) {
            int si = (zz * 32 + yy) * 32 + xv;
            for (int ci = 0; ci < CCH; ci++) {
                float v = ib[(size_t)ci * SVOL + si];
                const float* wr = wt + (size_t)(tap * CCH + ci) * CCH + g * 12;
                #pragma unroll
                for (int o = 0; o < 12; o++) acc[o] += wr[o] * v;
            }
        }
    }
    size_t base = (size_t)b * CCH * SVOL + s;
    #pragma unroll
    for (int o = 0; o < 12; o++) {
        int oc = g * 12 + o;
        float inv = rsqrtf(bv[oc] + 1e-5f);
        float h = (acc[o] - bm[oc]) * (bs[oc] * inv) + bb[oc];
        float a = h + skip[base + (size_t)oc * SVOL];
        attn[base + (size_t)oc * SVOL] = a >= 0.f ? a : 0.01f * a;
    }
}

// ---- pr_final: out = skip + pr(attn)  (4 groups x 12), scalar weights ----
__global__ __launch_bounds__(256, 4)
void pr_final_kernel(const float* __restrict__ attn, const float* __restrict__ skip,
                     const float* __restrict__ wt, const float* __restrict__ prb,
                     float* __restrict__ out) {
    int tid = threadIdx.x;
    int g = blockIdx.y, b = blockIdx.z;
    int s = blockIdx.x * 256 + tid;
    size_t base = (size_t)b * CCH * SVOL + s;
    float acc[12];
    #pragma unroll
    for (int o = 0; o < 12; o++) acc[o] = prb[g * 12 + o];
    for (int ci = 0; ci < CCH; ci++) {
        float v = attn[base + (size_t)ci * SVOL];
        const float* wr = wt + ci * CCH + g * 12;
        #pragma unroll
        for (int o = 0; o < 12; o++) acc[o] += wr[o] * v;
    }
    #pragma unroll
    for (int o = 0; o < 12; o++) {
        int oc = g * 12 + o;
        out[base + (size_t)oc * SVOL] = skip[base + (size_t)oc * SVOL] + acc[o];
    }
}

extern "C" void kernel_launch(void* const* d_in, const int* in_sizes, int n_in,
                              void* d_out, int out_size, void* d_ws, size_t ws_size,
                              hipStream_t stream) {
    (void)in_sizes; (void)n_in; (void)out_size; (void)ws_size;
    const float* x     = (const float*)d_in[0];
    const float* ln_s  = (const float*)d_in[1];
    const float* ln_b  = (const float*)d_in[2];
    const float* gamma = (const float*)d_in[3];
    const float* p1_w  = (const float*)d_in[4];
    const float* p1_b  = (const float*)d_in[5];
    const float* p2_w  = (const float*)d_in[6];
    const float* p2_b  = (const float*)d_in[7];
    const float* c0_w  = (const float*)d_in[8];
    const float* c0_b  = (const float*)d_in[9];
    const float* cs_w  = (const float*)d_in[10];
    const float* cs_b  = (const float*)d_in[11];
    const float* off_w = (const float*)d_in[12];
    const float* off_b = (const float*)d_in[13];
    const float* dc_w  = (const float*)d_in[14];
    const float* dc_b  = (const float*)d_in[15];
    const float* c1_w  = (const float*)d_in[16];
    const float* c1_b  = (const float*)d_in[17];
    const float* u1_w  = (const float*)d_in[18];
    const float* bn1_s = (const float*)d_in[19];
    const float* bn1_b = (const float*)d_in[20];
    const float* bn1_m = (const float*)d_in[21];
    const float* bn1_v = (const float*)d_in[22];
    const float* u2_w  = (const float*)d_in[23];
    const float* bn2_s = (const float*)d_in[24];
    const float* bn2_b = (const float*)d_in[25];
    const float* bn2_m = (const float*)d_in[26];
    const float* bn2_v = (const float*)d_in[27];
    const float* pr_w  = (const float*)d_in[28];
    const float* pr_b  = (const float*)d_in[29];
    float* out = (float*)d_out;

    float* wsf = (float*)d_ws;
    const size_t TS = (size_t)NB * CCH * SVOL;   // 3,145,728 floats
    float* xn   = out;            // d_out doubles as xn (dead before final write)
    float* ubuf = wsf;            // u (gelu out) -> h1 (u1 out)
    float* bufA = wsf + TS;       // dw5 out -> a1h (half, ch-last) -> skip
    float* bufB = wsf + 2 * TS;   // dw7 out (a1) -> deform partials (dc)
    float* offb = wsf + 3 * TS;   // offset partials [B,81,S] -> a2 -> attn
    float* wtb    = wsf + 3 * TS + (size_t)NB * 81 * SVOL;
    float* wt_off = wtb;                    // 27*48*81 = 104976
    float* wt_dc  = wt_off + 104976;        // 27*48*48 = 62208
    float* wt_u1  = wt_dc + 62208;
    float* wt_u2  = wt_u1 + 62208;
    float* pt_p1  = wt_u2 + 62208;          // 2304
    float* pt_c1  = pt_p1 + 2304;
    float* pt_p2  = pt_c1 + 2304;
    float* pt_pr  = pt_p2 + 2304;
    float* cb_all = pt_pr + 2304;           // 48
    __half* a1h = (__half*)bufA;            // NB*SVOL*48 halves = 6.3 MB (fits in bufA)

    dim3 blk(256);
    dim3 gpos(SVOL / 256, NB);
    dim3 g4(SVOL / 256, 4, NB);
    dim3 g6(SVOL / 256, 6, NB);
    dim3 g3d(SVOL / 256, 3, NB);
    dim3 gdw(SVOL / 256, CCH, NB);
    dim3 gtr(SVOL / 64, NB);

    hipLaunchKernelGGL(reshape_tap_kernel, dim3((104976 + 255) / 256), blk, 0, stream, off_w, wt_off, 81, CCH);
    hipLaunchKernelGGL(reshape_tap_kernel, dim3((62208 + 255) / 256),  blk, 0, stream, dc_w,  wt_dc,  CCH, CCH);
    hipLaunchKernelGGL(reshape_tap_kernel, dim3((62208 + 255) / 256),  blk, 0, stream, u1_w,  wt_u1,  CCH, CCH);
    hipLaunchKernelGGL(reshape_tap_kernel, dim3((62208 + 255) / 256),  blk, 0, stream, u2_w,  wt_u2,  CCH, CCH);
    hipLaunchKernelGGL(t1x1_kernel, dim3(9), blk, 0, stream, p1_w, pt_p1);
    hipLaunchKernelGGL(t1x1_kernel, dim3(9), blk, 0, stream, c1_w, pt_c1);
    hipLaunchKernelGGL(t1x1_kernel, dim3(9), blk, 0, stream, p2_w, pt_p2);
    hipLaunchKernelGGL(t1x1_kernel, dim3(9), blk, 0, stream, pr_w, pt_pr);
    hipLaunchKernelGGL(cb_kernel, dim3(1), dim3(64), 0, stream, c1_w, c1_b, dc_b, cb_all);

    hipLaunchKernelGGL(ln_kernel,          gpos, blk, 0, stream, x, ln_s, ln_b, xn);
    hipLaunchKernelGGL(p1_gelu_kernel,     g4,   blk, 0, stream, xn, pt_p1, p1_b, ubuf);
    hipLaunchKernelGGL(dw5_kernel,         gdw,  blk, 0, stream, ubuf, c0_w, c0_b, bufA);
    hipLaunchKernelGGL(dw7_kernel,         gdw,  blk, 0, stream, bufA, cs_w, cs_b, bufB);
    hipLaunchKernelGGL(transpose_h_kernel, gtr,  blk, 0, stream, bufB, a1h);   // a1 -> a1h (fp16)
    hipMemsetAsync(offb, 0, (size_t)NB * 81 * SVOL * sizeof(float), stream);
    hipLaunchKernelGGL(offconv_kernel,     g6,   blk, 0, stream, bufB, wt_off, offb);
    hipMemsetAsync(bufB, 0, TS * sizeof(float), stream);
    hipLaunchKernelGGL(deform_kernel,      g3d,  blk, 0, stream, a1h, offb, off_b, wt_dc, bufB);
    hipLaunchKernelGGL(gate1_kernel,       g4,   blk, 0, stream, bufB, ubuf, pt_c1, cb_all, offb);
    hipLaunchKernelGGL(gate2_kernel,       g4,   blk, 0, stream, offb, xn, x, pt_p2, p2_b, gamma, bufA);
    hipLaunchKernelGGL(u1_kernel,          g4,   blk, 0, stream, bufA, wt_u1,
                       bn1_s, bn1_b, bn1_m, bn1_v, ubuf);
    hipLaunchKernelGGL(u2_bn_kernel,       g4,   blk, 0, stream, ubuf, bufA, wt_u2,
                       bn2_s, bn2_b, bn2_m, bn2_v, offb);
    hipLaunchKernelGGL(pr_final_kernel,    g4,   blk, 0, stream, offb, bufA, pt_pr, pr_b, out);
}

// Round 12
// 778.757 us; speedup vs baseline: 2.0885x; 1.4714x over previous
//
#include <hip/hip_runtime.h>
#include <hip/hip_fp16.h>
#include <math.h>

#define CCH 48
#define SDIM 32
#define SVOL (SDIM*SDIM*SDIM)
#define NB 2

// ======== one-off weight reshape kernels ========

__global__ __launch_bounds__(256)
void reshape_tap_kernel(const float* __restrict__ w, float* __restrict__ wt,
                        int NO, int NI) {
    int i = blockIdx.x * 256 + threadIdx.x;
    int total = NO * NI * 27;
    if (i < total) {
        int tap = i / (NI * NO);
        int rem = i % (NI * NO);
        int ci = rem / NO, o = rem % NO;
        wt[i] = w[(o * NI + ci) * 27 + tap];
    }
}

__global__ __launch_bounds__(256)
void t1x1_kernel(const float* __restrict__ w, float* __restrict__ wt) {
    int i = blockIdx.x * 256 + threadIdx.x;
    if (i < CCH * CCH) { int ci = i / CCH, o = i % CCH; wt[i] = w[o * CCH + ci]; }
}

__global__ __launch_bounds__(64)
void cb_kernel(const float* __restrict__ c1w, const float* __restrict__ c1b,
               const float* __restrict__ dcb, float* __restrict__ cb) {
    int o = threadIdx.x;
    if (o < CCH) {
        float v = c1b[o];
        for (int ci = 0; ci < CCH; ci++) v += c1w[o * CCH + ci] * dcb[ci];
        cb[o] = v;
    }
}

// ---------------- LayerNorm over C ----------------
__global__ __launch_bounds__(256)
void ln_kernel(const float* __restrict__ x, const float* __restrict__ ln_s,
               const float* __restrict__ ln_b, float* __restrict__ xn) {
    int s = blockIdx.x * 256 + threadIdx.x;
    int b = blockIdx.y;
    const float* xb = x + (size_t)b * CCH * SVOL + s;
    float v[CCH];
    float mu = 0.f;
    #pragma unroll
    for (int c = 0; c < CCH; c++) { v[c] = xb[c * SVOL]; mu += v[c]; }
    mu *= (1.0f / CCH);
    float var = 0.f;
    #pragma unroll
    for (int c = 0; c < CCH; c++) { float d = v[c] - mu; var += d * d; }
    var *= (1.0f / CCH);
    float inv = rsqrtf(var + 1e-5f);
    float* o = xn + (size_t)b * CCH * SVOL + s;
    #pragma unroll
    for (int c = 0; c < CCH; c++) o[c * SVOL] = (v[c] - mu) * inv * ln_s[c] + ln_b[c];
}

// ---------------- 1x1x1 conv + exact GELU (4 groups x 12), scalar weights ----------------
__global__ __launch_bounds__(256, 4)
void p1_gelu_kernel(const float* __restrict__ xn, const float* __restrict__ wt,
                    const float* __restrict__ bias, float* __restrict__ u) {
    int tid = threadIdx.x;
    int g = blockIdx.y, b = blockIdx.z;
    int s = blockIdx.x * 256 + tid;
    const float* xb = xn + (size_t)b * CCH * SVOL + s;
    float acc[12];
    #pragma unroll
    for (int o = 0; o < 12; o++) acc[o] = bias[g * 12 + o];
    for (int c = 0; c < CCH; c++) {
        float v = xb[c * SVOL];
        const float* wr = wt + c * CCH + g * 12;
        #pragma unroll
        for (int o = 0; o < 12; o++) acc[o] += wr[o] * v;
    }
    float* ub = u + (size_t)b * CCH * SVOL + s + (size_t)(g * 12) * SVOL;
    #pragma unroll
    for (int o = 0; o < 12; o++) {
        float a = acc[o];
        ub[o * SVOL] = 0.5f * a * (1.0f + erff(a * 0.70710678118654752f));
    }
}

// ---- depthwise 5x5x5 pad 2: z-column register blocking (32 outputs/thread) ----
__global__ __launch_bounds__(256, 2)
void dw5_kernel(const float* __restrict__ in, const float* __restrict__ w,
                const float* __restrict__ bias, float* __restrict__ out) {
    int tid = threadIdx.x;
    int c = blockIdx.y, b = blockIdx.z;
    const float* wc = w + c * 125;                    // uniform
    int yx = blockIdx.x * 256 + tid;                  // 0..1023
    int y = yx >> 5, xx = yx & 31;
    const float* ib = in + ((size_t)b * CCH + c) * SVOL;
    float acc[32];
    float bv = bias[c];
    #pragma unroll
    for (int z = 0; z < 32; z++) acc[z] = bv;
    for (int ty = 0; ty < 5; ty++) {
        int yy = y + ty - 2; if (yy < 0 || yy >= 32) continue;
        for (int tx = 0; tx < 5; tx++) {
            int xv = xx + tx - 2; if (xv < 0 || xv >= 32) continue;
            const float* col = ib + yy * 32 + xv;     // z stride 1024
            float cv[32];
            #pragma unroll
            for (int zz = 0; zz < 32; zz++) cv[zz] = col[(size_t)zz * 1024];
            #pragma unroll
            for (int tz = 0; tz < 5; tz++) {
                float wv = wc[(tz * 5 + ty) * 5 + tx];    // uniform s_load
                const int o = tz - 2;
                #pragma unroll
                for (int z = 0; z < 32; z++) {
                    int zz = z + o;
                    if (zz >= 0 && zz < 32) acc[z] += wv * cv[zz];   // folds at compile time
                }
            }
        }
    }
    float* ob = out + ((size_t)b * CCH + c) * SVOL + y * 32 + xx;
    #pragma unroll
    for (int z = 0; z < 32; z++) ob[(size_t)z * 1024] = acc[z];
}

// ---- depthwise 7x7x7 dil 3 pad 9: z-column register blocking (32 outputs/thread) ----
__global__ __launch_bounds__(256, 2)
void dw7_kernel(const float* __restrict__ in, const float* __restrict__ w,
                const float* __restrict__ bias, float* __restrict__ out) {
    int tid = threadIdx.x;
    int c = blockIdx.y, b = blockIdx.z;
    const float* wc = w + c * 343;                    // uniform
    int yx = blockIdx.x * 256 + tid;
    int y = yx >> 5, xx = yx & 31;
    const float* ib = in + ((size_t)b * CCH + c) * SVOL;
    float acc[32];
    float bv = bias[c];
    #pragma unroll
    for (int z = 0; z < 32; z++) acc[z] = bv;
    for (int ty = 0; ty < 7; ty++) {
        int yy = y + 3 * (ty - 3); if (yy < 0 || yy >= 32) continue;
        for (int tx = 0; tx < 7; tx++) {
            int xv = xx + 3 * (tx - 3); if (xv < 0 || xv >= 32) continue;
            const float* col = ib + yy * 32 + xv;
            float cv[32];
            #pragma unroll
            for (int zz = 0; zz < 32; zz++) cv[zz] = col[(size_t)zz * 1024];
            #pragma unroll
            for (int tz = 0; tz < 7; tz++) {
                float wv = wc[(tz * 7 + ty) * 7 + tx];    // uniform s_load
                const int o = 3 * (tz - 3);
                #pragma unroll
                for (int z = 0; z < 32; z++) {
                    int zz = z + o;
                    if (zz >= 0 && zz < 32) acc[z] += wv * cv[zz];   // folds at compile time
                }
            }
        }
    }
    float* ob = out + ((size_t)b * CCH + c) * SVOL + y * 32 + xx;
    #pragma unroll
    for (int z = 0; z < 32; z++) ob[(size_t)z * 1024] = acc[z];
}

// ---------------- transpose [C][S] -> [S][C] fp16 records ----------------
__global__ __launch_bounds__(256)
void transpose_h_kernel(const float* __restrict__ a1, __half* __restrict__ a1h) {
    __shared__ float tile[CCH * 65];
    int tid = threadIdx.x;
    int b = blockIdx.y;
    int s0 = blockIdx.x * 64;
    const float* ib = a1 + (size_t)b * CCH * SVOL + s0;
    for (int i = tid; i < CCH * 64; i += 256) {
        int c = i >> 6, p = i & 63;
        tile[c * 65 + p] = ib[(size_t)c * SVOL + p];
    }
    __syncthreads();
    __half* ob = a1h + ((size_t)b * SVOL + s0) * CCH;
    for (int i = tid; i < 64 * CCH; i += 256) {
        int p = i / CCH, c = i % CCH;
        ob[i] = __float2half(tile[c * 65 + p]);
    }
}

// ---- offset conv 3x3x3: 48->81, ci-split 2 x out-split 3, scalar weights, atomic, NO bias ----
__global__ __launch_bounds__(256, 4)
void offconv_kernel(const float* __restrict__ a1, const float* __restrict__ wt,
                    float* __restrict__ off) {
    int tid = threadIdx.x;
    int go = blockIdx.y % 3;
    int gc = blockIdx.y / 3;
    int b = blockIdx.z;
    int s = blockIdx.x * 256 + tid;
    int z = s >> 10, y = (s >> 5) & 31, xx = s & 31;
    const float* ib = a1 + ((size_t)b * CCH + gc * 24) * SVOL;
    float acc[27];
    #pragma unroll
    for (int o = 0; o < 27; o++) acc[o] = 0.f;
    for (int tap = 0; tap < 27; tap++) {
        int dz = tap / 9 - 1, dy = (tap / 3) % 3 - 1, dx = tap % 3 - 1;
        int zz = z + dz, yy = y + dy, xv = xx + dx;
        bool ok = (zz >= 0 && zz < 32 && yy >= 0 && yy < 32 && xv >= 0 && xv < 32);
        if (ok) {
            int si = (zz * 32 + yy) * 32 + xv;
            for (int cis = 0; cis < 24; cis++) {
                float v = ib[(size_t)cis * SVOL + si];
                const float* wr = wt + (size_t)(tap * CCH + gc * 24 + cis) * 81 + go * 27;
                #pragma unroll
                for (int o = 0; o < 27; o++) acc[o] += wr[o] * v;
            }
        }
    }
    float* obuf = off + (size_t)b * 81 * SVOL + (size_t)(go * 27) * SVOL + s;
    #pragma unroll
    for (int o = 0; o < 27; o++) atomicAdd(&obuf[(size_t)o * SVOL], acc[o]);
}

// ---- deformable conv 3x3x3: ci-split 3 (16 ch), fp16 channel-last gather (2x16B/corner) ----
struct h8 { __half2 a, b, c, d; };   // 16 bytes = 8 halves

__global__ __launch_bounds__(256, 4)
void deform_kernel(const __half* __restrict__ a1h, const float* __restrict__ off,
                   const float* __restrict__ off_b,
                   const float* __restrict__ wt, float* __restrict__ out) {
    int tid = threadIdx.x;
    int gc = blockIdx.y;            // ci group 0..2 (16 ch each)
    int b = blockIdx.z;
    int s = blockIdx.x * 256 + tid;
    int z = s >> 10, y = (s >> 5) & 31, xx = s & 31;
    const __half* abase = a1h + (size_t)b * SVOL * CCH + gc * 16;
    const float* ob = off + (size_t)b * 81 * SVOL + s;
    float acc[CCH];
    #pragma unroll
    for (int o = 0; o < CCH; o++) acc[o] = 0.f;
    for (int k = 0; k < 27; k++) {
        int kd = k / 9 - 1, kh = (k / 3) % 3 - 1, kw = k % 3 - 1;
        float zf = (float)(z + kd) + ob[(size_t)(k * 3 + 0) * SVOL] + off_b[k * 3 + 0];
        float yf = (float)(y + kh) + ob[(size_t)(k * 3 + 1) * SVOL] + off_b[k * 3 + 1];
        float xf = (float)(xx + kw) + ob[(size_t)(k * 3 + 2) * SVOL] + off_b[k * 3 + 2];
        float z0 = floorf(zf), y0 = floorf(yf), x0 = floorf(xf);
        float tz = zf - z0, ty = yf - y0, tx = xf - x0;
        int iz0 = (int)z0, iy0 = (int)y0, ix0 = (int)x0;
        float val[16];
        #pragma unroll
        for (int j = 0; j < 16; j++) val[j] = 0.f;
        #pragma unroll
        for (int corner = 0; corner < 8; corner++) {
            int dz = corner >> 2, dy = (corner >> 1) & 1, dx = corner & 1;
            int zi = iz0 + dz, yi = iy0 + dy, xi = ix0 + dx;
            bool valid = (zi >= 0 && zi < 32 && yi >= 0 && yi < 32 && xi >= 0 && xi < 32);
            float wgt = (dz ? tz : 1.f - tz) * (dy ? ty : 1.f - ty) * (dx ? tx : 1.f - tx);
            float cwv = valid ? wgt : 0.f;
            int zc = min(max(zi, 0), 31), yc = min(max(yi, 0), 31), xc = min(max(xi, 0), 31);
            int cidx = (zc * 32 + yc) * 32 + xc;
            const h8* pv = (const h8*)(abase + (size_t)cidx * CCH);
            h8 q0 = pv[0], q1 = pv[1];
            float2 f;
            f = __half22float2(q0.a); val[0]  += cwv * f.x; val[1]  += cwv * f.y;
            f = __half22float2(q0.b); val[2]  += cwv * f.x; val[3]  += cwv * f.y;
            f = __half22float2(q0.c); val[4]  += cwv * f.x; val[5]  += cwv * f.y;
            f = __half22float2(q0.d); val[6]  += cwv * f.x; val[7]  += cwv * f.y;
            f = __half22float2(q1.a); val[8]  += cwv * f.x; val[9]  += cwv * f.y;
            f = __half22float2(q1.b); val[10] += cwv * f.x; val[11] += cwv * f.y;
            f = __half22float2(q1.c); val[12] += cwv * f.x; val[13] += cwv * f.y;
            f = __half22float2(q1.d); val[14] += cwv * f.x; val[15] += cwv * f.y;
        }
        #pragma unroll
        for (int cis = 0; cis < 16; cis++) {
            float v = val[cis];
            const float* wr = wt + (size_t)(k * CCH + gc * 16 + cis) * CCH;   // uniform
            #pragma unroll
            for (int o = 0; o < CCH; o++) acc[o] += wr[o] * v;
        }
    }
    float* op = out + (size_t)b * CCH * SVOL + s;
    #pragma unroll
    for (int o = 0; o < CCH; o++) atomicAdd(&op[(size_t)o * SVOL], acc[o]);
}

// ---- gate1: a2 = (c1 . dc + cb) * u   (4 groups x 12), scalar weights ----
__global__ __launch_bounds__(256, 4)
void gate1_kernel(const float* __restrict__ dc, const float* __restrict__ u,
                  const float* __restrict__ wt, const float* __restrict__ cb,
                  float* __restrict__ a2buf) {
    int tid = threadIdx.x;
    int g = blockIdx.y, b = blockIdx.z;
    int s = blockIdx.x * 256 + tid;
    size_t base = (size_t)b * CCH * SVOL + s;
    float acc[12];
    #pragma unroll
    for (int o = 0; o < 12; o++) acc[o] = cb[g * 12 + o];
    for (int ci = 0; ci < CCH; ci++) {
        float v = dc[base + (size_t)ci * SVOL];
        const float* wr = wt + ci * CCH + g * 12;
        #pragma unroll
        for (int o = 0; o < 12; o++) acc[o] += wr[o] * v;
    }
    #pragma unroll
    for (int o = 0; o < 12; o++) {
        size_t oo = base + (size_t)(g * 12 + o) * SVOL;
        a2buf[oo] = acc[o] * u[oo];
    }
}

// ---- gate2: skip = x + gamma*(p2 . a2 + p2b + xn)  (4 groups x 12), scalar weights ----
__global__ __launch_bounds__(256, 4)
void gate2_kernel(const float* __restrict__ a2buf, const float* __restrict__ xn,
                  const float* __restrict__ x,
                  const float* __restrict__ wt, const float* __restrict__ p2b,
                  const float* __restrict__ gamma, float* __restrict__ skip) {
    int tid = threadIdx.x;
    int g = blockIdx.y, b = blockIdx.z;
    int s = blockIdx.x * 256 + tid;
    size_t base = (size_t)b * CCH * SVOL + s;
    float acc[12];
    #pragma unroll
    for (int o = 0; o < 12; o++) acc[o] = p2b[g * 12 + o];
    for (int ci = 0; ci < CCH; ci++) {
        float v = a2buf[base + (size_t)ci * SVOL];
        const float* wr = wt + ci * CCH + g * 12;
        #pragma unroll
        for (int o = 0; o < 12; o++) acc[o] += wr[o] * v;
    }
    #pragma unroll
    for (int o = 0; o < 12; o++) {
        int oc = g * 12 + o;
        float vv = acc[o] + xn[base + (size_t)oc * SVOL];
        skip[base + (size_t)oc * SVOL] = x[base + (size_t)oc * SVOL] + gamma[oc] * vv;
    }
}

// ---- u1: 3x3x3 conv + BN1 + LeakyReLU (4 groups x 12), scalar weights [tap][ci][48] ----
__global__ __launch_bounds__(256, 4)
void u1_kernel(const float* __restrict__ in, const float* __restrict__ wt,
               const float* __restrict__ bs, const float* __restrict__ bb,
               const float* __restrict__ bm, const float* __restrict__ bv,
               float* __restrict__ out) {
    int tid = threadIdx.x;
    int g = blockIdx.y, b = blockIdx.z;
    int s = blockIdx.x * 256 + tid;
    int z = s >> 10, y = (s >> 5) & 31, xx = s & 31;
    const float* ib = in + (size_t)b * CCH * SVOL;
    float acc[12];
    #pragma unroll
    for (int o = 0; o < 12; o++) acc[o] = 0.f;
    for (int tap = 0; tap < 27; tap++) {
        int dz = tap / 9 - 1, dy = (tap / 3) % 3 - 1, dx = tap % 3 - 1;
        int zz = z + dz, yy = y + dy, xv = xx + dx;
        bool ok = (zz >= 0 && zz < 32 && yy >= 0 && yy < 32 && xv >= 0 && xv < 32);
        if (ok) {
            int si = (zz * 32 + yy) * 32 + xv;
            for (int ci = 0; ci < CCH; ci++) {
                float v = ib[(size_t)ci * SVOL + si];
                const float* wr = wt + (size_t)(tap * CCH + ci) * CCH + g * 12;
                #pragma unroll
                for (int o = 0; o < 12; o++) acc[o] += wr[o] * v;
            }
        }
    }
    float* op = out + (size_t)b * CCH * SVOL + (size_t)(g * 12) * SVOL + s;
    #pragma unroll
    for (int o = 0; o < 12; o++) {
        int oc = g * 12 + o;
        float inv = rsqrtf(bv[oc] + 1e-5f);
        float h = (acc[o] - bm[oc]) * (bs[oc] * inv) + bb[oc];
        op[(size_t)o * SVOL] = h >= 0.f ? h : 0.01f * h;
    }
}

// ---- u2_bn: 3x3x3 conv + BN2 + (+skip) + LeakyReLU -> attn (4 groups x 12), scalar weights ----
__global__ __launch_bounds__(256, 4)
void u2_bn_kernel(const float* __restrict__ h1, const float* __restrict__ skip,
                  const float* __restrict__ wt,
                  const float* __restrict__ bs, const float* __restrict__ bb,
                  const float* __restrict__ bm, const float* __restrict__ bv,
                  float* __restrict__ attn) {
    int tid = threadIdx.x;
    int g = blockIdx.y, b = blockIdx.z;
    int s = blockIdx.x * 256 + tid;
    int z = s >> 10, y = (s >> 5) & 31, xx = s & 31;
    const float* ib = h1 + (size_t)b * CCH * SVOL;
    float acc[12];
    #pragma unroll
    for (int o = 0; o < 12; o++) acc[o] = 0.f;
    for (int tap = 0; tap < 27; tap++) {
        int dz = tap / 9 - 1, dy = (tap / 3) % 3 - 1, dx = tap % 3 - 1;
        int zz = z + dz, yy = y + dy, xv = xx + dx;
        bool ok = (zz >= 0 && zz < 32 && yy >= 0 && yy < 32 && xv >= 0 && xv < 32);
        if (ok) {
            int si = (zz * 32 + yy) * 32 + xv;
            for (int ci = 0; ci < CCH; ci++) {
                float v = ib[(size_t)ci * SVOL + si];
                const float* wr = wt + (size_t)(tap * CCH + ci) * CCH + g * 12;
                #pragma unroll
                for (int o = 0; o < 12; o++) acc[o] += wr[o] * v;
            }
        }
    }
    size_t base = (size_t)b * CCH * SVOL + s;
    #pragma unroll
    for (int o = 0; o < 12; o++) {
        int oc = g * 12 + o;
        float inv = rsqrtf(bv[oc] + 1e-5f);
        float h = (acc[o] - bm[oc]) * (bs[oc] * inv) + bb[oc];
        float a = h + skip[base + (size_t)oc * SVOL];
        attn[base + (size_t)oc * SVOL] = a >= 0.f ? a : 0.01f * a;
    }
}

// ---- pr_final: out = skip + pr(attn)  (4 groups x 12), scalar weights ----
__global__ __launch_bounds__(256, 4)
void pr_final_kernel(const float* __restrict__ attn, const float* __restrict__ skip,
                     const float* __restrict__ wt, const float* __restrict__ prb,
                     float* __restrict__ out) {
    int tid = threadIdx.x;
    int g = blockIdx.y, b = blockIdx.z;
    int s = blockIdx.x * 256 + tid;
    size_t base = (size_t)b * CCH * SVOL + s;
    float acc[12];
    #pragma unroll
    for (int o = 0; o < 12; o++) acc[o] = prb[g * 12 + o];
    for (int ci = 0; ci < CCH; ci++) {
        float v = attn[base + (size_t)ci * SVOL];
        const float* wr = wt + ci * CCH + g * 12;
        #pragma unroll
        for (int o = 0; o < 12; o++) acc[o] += wr[o] * v;
    }
    #pragma unroll
    for (int o = 0; o < 12; o++) {
        int oc = g * 12 + o;
        out[base + (size_t)oc * SVOL] = skip[base + (size_t)oc * SVOL] + acc[o];
    }
}

extern "C" void kernel_launch(void* const* d_in, const int* in_sizes, int n_in,
                              void* d_out, int out_size, void* d_ws, size_t ws_size,
                              hipStream_t stream) {
    (void)in_sizes; (void)n_in; (void)out_size; (void)ws_size;
    const float* x     = (const float*)d_in[0];
    const float* ln_s  = (const float*)d_in[1];
    const float* ln_b  = (const float*)d_in[2];
    const float* gamma = (const float*)d_in[3];
    const float* p1_w  = (const float*)d_in[4];
    const float* p1_b  = (const float*)d_in[5];
    const float* p2_w  = (const float*)d_in[6];
    const float* p2_b  = (const float*)d_in[7];
    const float* c0_w  = (const float*)d_in[8];
    const float* c0_b  = (const float*)d_in[9];
    const float* cs_w  = (const float*)d_in[10];
    const float* cs_b  = (const float*)d_in[11];
    const float* off_w = (const float*)d_in[12];
    const float* off_b = (const float*)d_in[13];
    const float* dc_w  = (const float*)d_in[14];
    const float* dc_b  = (const float*)d_in[15];
    const float* c1_w  = (const float*)d_in[16];
    const float* c1_b  = (const float*)d_in[17];
    const float* u1_w  = (const float*)d_in[18];
    const float* bn1_s = (const float*)d_in[19];
    const float* bn1_b = (const float*)d_in[20];
    const float* bn1_m = (const float*)d_in[21];
    const float* bn1_v = (const float*)d_in[22];
    const float* u2_w  = (const float*)d_in[23];
    const float* bn2_s = (const float*)d_in[24];
    const float* bn2_b = (const float*)d_in[25];
    const float* bn2_m = (const float*)d_in[26];
    const float* bn2_v = (const float*)d_in[27];
    const float* pr_w  = (const float*)d_in[28];
    const float* pr_b  = (const float*)d_in[29];
    float* out = (float*)d_out;

    float* wsf = (float*)d_ws;
    const size_t TS = (size_t)NB * CCH * SVOL;   // 3,145,728 floats
    float* xn   = out;            // d_out doubles as xn (dead before final write)
    float* ubuf = wsf;            // u (gelu out) -> h1 (u1 out)
    float* bufA = wsf + TS;       // dw5 out -> a1h (half, ch-last) -> skip
    float* bufB = wsf + 2 * TS;   // dw7 out (a1) -> deform partials (dc)
    float* offb = wsf + 3 * TS;   // offset partials [B,81,S] -> a2 -> attn
    float* wtb    = wsf + 3 * TS + (size_t)NB * 81 * SVOL;
    float* wt_off = wtb;                    // 27*48*81 = 104976
    float* wt_dc  = wt_off + 104976;        // 27*48*48 = 62208
    float* wt_u1  = wt_dc + 62208;
    float* wt_u2  = wt_u1 + 62208;
    float* pt_p1  = wt_u2 + 62208;          // 2304
    float* pt_c1  = pt_p1 + 2304;
    float* pt_p2  = pt_c1 + 2304;
    float* pt_pr  = pt_p2 + 2304;
    float* cb_all = pt_pr + 2304;           // 48
    __half* a1h = (__half*)bufA;            // NB*SVOL*48 halves = 6.3 MB (fits in bufA)

    dim3 blk(256);
    dim3 gpos(SVOL / 256, NB);
    dim3 g4(SVOL / 256, 4, NB);
    dim3 g6(SVOL / 256, 6, NB);
    dim3 g3d(SVOL / 256, 3, NB);
    dim3 gdwc(1024 / 256, CCH, NB);    // z-column depthwise: 4 x 48 x 2
    dim3 gtr(SVOL / 64, NB);

    hipLaunchKernelGGL(reshape_tap_kernel, dim3((104976 + 255) / 256), blk, 0, stream, off_w, wt_off, 81, CCH);
    hipLaunchKernelGGL(reshape_tap_kernel, dim3((62208 + 255) / 256),  blk, 0, stream, dc_w,  wt_dc,  CCH, CCH);
    hipLaunchKernelGGL(reshape_tap_kernel, dim3((62208 + 255) / 256),  blk, 0, stream, u1_w,  wt_u1,  CCH, CCH);
    hipLaunchKernelGGL(reshape_tap_kernel, dim3((62208 + 255) / 256),  blk, 0, stream, u2_w,  wt_u2,  CCH, CCH);
    hipLaunchKernelGGL(t1x1_kernel, dim3(9), blk, 0, stream, p1_w, pt_p1);
    hipLaunchKernelGGL(t1x1_kernel, dim3(9), blk, 0, stream, c1_w, pt_c1);
    hipLaunchKernelGGL(t1x1_kernel, dim3(9), blk, 0, stream, p2_w, pt_p2);
    hipLaunchKernelGGL(t1x1_kernel, dim3(9), blk, 0, stream, pr_w, pt_pr);
    hipLaunchKernelGGL(cb_kernel, dim3(1), dim3(64), 0, stream, c1_w, c1_b, dc_b, cb_all);

    hipLaunchKernelGGL(ln_kernel,          gpos, blk, 0, stream, x, ln_s, ln_b, xn);
    hipLaunchKernelGGL(p1_gelu_kernel,     g4,   blk, 0, stream, xn, pt_p1, p1_b, ubuf);
    hipLaunchKernelGGL(dw5_kernel,         gdwc, blk, 0, stream, ubuf, c0_w, c0_b, bufA);
    hipLaunchKernelGGL(dw7_kernel,         gdwc, blk, 0, stream, bufA, cs_w, cs_b, bufB);
    hipLaunchKernelGGL(transpose_h_kernel, gtr,  blk, 0, stream, bufB, a1h);   // a1 -> a1h (fp16)
    hipMemsetAsync(offb, 0, (size_t)NB * 81 * SVOL * sizeof(float), stream);
    hipLaunchKernelGGL(offconv_kernel,     g6,   blk, 0, stream, bufB, wt_off, offb);
    hipMemsetAsync(bufB, 0, TS * sizeof(float), stream);
    hipLaunchKernelGGL(deform_kernel,      g3d,  blk, 0, stream, a1h, offb, off_b, wt_dc, bufB);
    hipLaunchKernelGGL(gate1_kernel,       g4,   blk, 0, stream, bufB, ubuf, pt_c1, cb_all, offb);
    hipLaunchKernelGGL(gate2_kernel,       g4,   blk, 0, stream, offb, xn, x, pt_p2, p2_b, gamma, bufA);
    hipLaunchKernelGGL(u1_kernel,          g4,   blk, 0, stream, bufA, wt_u1,
                       bn1_s, bn1_b, bn1_m, bn1_v, ubuf);
    hipLaunchKernelGGL(u2_bn_kernel,       g4,   blk, 0, stream, ubuf, bufA, wt_u2,
                       bn2_s, bn2_b, bn2_m, bn2_v, offb);
    hipLaunchKernelGGL(pr_final_kernel,    g4,   blk, 0, stream, offb, bufA, pt_pr, pr_b, out);
}

// Round 13
// 751.555 us; speedup vs baseline: 2.1641x; 1.0362x over previous
//
#include <hip/hip_runtime.h>
#include <hip/hip_fp16.h>
#include <math.h>

#define CCH 48
#define SDIM 32
#define SVOL (SDIM*SDIM*SDIM)
#define NB 2

typedef _Float16 half2_t __attribute__((ext_vector_type(2)));

static __device__ __forceinline__ float dot2f(half2_t a, half2_t b, float c) {
#if __has_builtin(__builtin_amdgcn_fdot2)
    return __builtin_amdgcn_fdot2(a, b, c, false);
#else
    return c + (float)a[0] * (float)b[0] + (float)a[1] * (float)b[1];
#endif
}

// ======== one-off weight reshape kernels ========

__global__ __launch_bounds__(256)
void reshape_tap_kernel(const float* __restrict__ w, float* __restrict__ wt,
                        int NO, int NI) {
    int i = blockIdx.x * 256 + threadIdx.x;
    int total = NO * NI * 27;
    if (i < total) {
        int tap = i / (NI * NO);
        int rem = i % (NI * NO);
        int ci = rem / NO, o = rem % NO;
        wt[i] = w[(o * NI + ci) * 27 + tap];
    }
}

// dc weights -> half2 pairs along ci: wt[(k*24+cp)*48+o] = (w[o][2cp][k], w[o][2cp+1][k])
__global__ __launch_bounds__(256)
void reshape_dc_h_kernel(const float* __restrict__ w, __half2* __restrict__ wt) {
    int i = blockIdx.x * 256 + threadIdx.x;     // 27*24*48 = 31104
    if (i < 27 * 24 * CCH) {
        int o = i % CCH; int rem = i / CCH; int cp = rem % 24; int k = rem / 24;
        float w0 = w[((size_t)o * CCH + 2 * cp) * 27 + k];
        float w1 = w[((size_t)o * CCH + 2 * cp + 1) * 27 + k];
        wt[i] = __halves2half2(__float2half(w0), __float2half(w1));
    }
}

__global__ __launch_bounds__(256)
void t1x1_kernel(const float* __restrict__ w, float* __restrict__ wt) {
    int i = blockIdx.x * 256 + threadIdx.x;
    if (i < CCH * CCH) { int ci = i / CCH, o = i % CCH; wt[i] = w[o * CCH + ci]; }
}

__global__ __launch_bounds__(64)
void cb_kernel(const float* __restrict__ c1w, const float* __restrict__ c1b,
               const float* __restrict__ dcb, float* __restrict__ cb) {
    int o = threadIdx.x;
    if (o < CCH) {
        float v = c1b[o];
        for (int ci = 0; ci < CCH; ci++) v += c1w[o * CCH + ci] * dcb[ci];
        cb[o] = v;
    }
}

// ---------------- LayerNorm over C ----------------
__global__ __launch_bounds__(256)
void ln_kernel(const float* __restrict__ x, const float* __restrict__ ln_s,
               const float* __restrict__ ln_b, float* __restrict__ xn) {
    int s = blockIdx.x * 256 + threadIdx.x;
    int b = blockIdx.y;
    const float* xb = x + (size_t)b * CCH * SVOL + s;
    float v[CCH];
    float mu = 0.f;
    #pragma unroll
    for (int c = 0; c < CCH; c++) { v[c] = xb[c * SVOL]; mu += v[c]; }
    mu *= (1.0f / CCH);
    float var = 0.f;
    #pragma unroll
    for (int c = 0; c < CCH; c++) { float d = v[c] - mu; var += d * d; }
    var *= (1.0f / CCH);
    float inv = rsqrtf(var + 1e-5f);
    float* o = xn + (size_t)b * CCH * SVOL + s;
    #pragma unroll
    for (int c = 0; c < CCH; c++) o[c * SVOL] = (v[c] - mu) * inv * ln_s[c] + ln_b[c];
}

// ---------------- 1x1x1 conv + exact GELU (4 groups x 12), scalar weights ----------------
__global__ __launch_bounds__(256, 4)
void p1_gelu_kernel(const float* __restrict__ xn, const float* __restrict__ wt,
                    const float* __restrict__ bias, float* __restrict__ u) {
    int tid = threadIdx.x;
    int g = blockIdx.y, b = blockIdx.z;
    int s = blockIdx.x * 256 + tid;
    const float* xb = xn + (size_t)b * CCH * SVOL + s;
    float acc[12];
    #pragma unroll
    for (int o = 0; o < 12; o++) acc[o] = bias[g * 12 + o];
    for (int c = 0; c < CCH; c++) {
        float v = xb[c * SVOL];
        const float* wr = wt + c * CCH + g * 12;
        #pragma unroll
        for (int o = 0; o < 12; o++) acc[o] += wr[o] * v;
    }
    float* ub = u + (size_t)b * CCH * SVOL + s + (size_t)(g * 12) * SVOL;
    #pragma unroll
    for (int o = 0; o < 12; o++) {
        float a = acc[o];
        ub[o * SVOL] = 0.5f * a * (1.0f + erff(a * 0.70710678118654752f));
    }
}

// ---- depthwise 5x5x5 pad 2: z-column register blocking (32 outputs/thread) ----
__global__ __launch_bounds__(256, 2)
void dw5_kernel(const float* __restrict__ in, const float* __restrict__ w,
                const float* __restrict__ bias, float* __restrict__ out) {
    int tid = threadIdx.x;
    int c = blockIdx.y, b = blockIdx.z;
    const float* wc = w + c * 125;
    int yx = blockIdx.x * 256 + tid;
    int y = yx >> 5, xx = yx & 31;
    const float* ib = in + ((size_t)b * CCH + c) * SVOL;
    float acc[32];
    float bv = bias[c];
    #pragma unroll
    for (int z = 0; z < 32; z++) acc[z] = bv;
    for (int ty = 0; ty < 5; ty++) {
        int yy = y + ty - 2; if (yy < 0 || yy >= 32) continue;
        for (int tx = 0; tx < 5; tx++) {
            int xv = xx + tx - 2; if (xv < 0 || xv >= 32) continue;
            const float* col = ib + yy * 32 + xv;
            float cv[32];
            #pragma unroll
            for (int zz = 0; zz < 32; zz++) cv[zz] = col[(size_t)zz * 1024];
            #pragma unroll
            for (int tz = 0; tz < 5; tz++) {
                float wv = wc[(tz * 5 + ty) * 5 + tx];
                const int o = tz - 2;
                #pragma unroll
                for (int z = 0; z < 32; z++) {
                    int zz = z + o;
                    if (zz >= 0 && zz < 32) acc[z] += wv * cv[zz];
                }
            }
        }
    }
    float* ob = out + ((size_t)b * CCH + c) * SVOL + y * 32 + xx;
    #pragma unroll
    for (int z = 0; z < 32; z++) ob[(size_t)z * 1024] = acc[z];
}

// ---- depthwise 7x7x7 dil 3 pad 9: z-column register blocking (32 outputs/thread) ----
__global__ __launch_bounds__(256, 2)
void dw7_kernel(const float* __restrict__ in, const float* __restrict__ w,
                const float* __restrict__ bias, float* __restrict__ out) {
    int tid = threadIdx.x;
    int c = blockIdx.y, b = blockIdx.z;
    const float* wc = w + c * 343;
    int yx = blockIdx.x * 256 + tid;
    int y = yx >> 5, xx = yx & 31;
    const float* ib = in + ((size_t)b * CCH + c) * SVOL;
    float acc[32];
    float bv = bias[c];
    #pragma unroll
    for (int z = 0; z < 32; z++) acc[z] = bv;
    for (int ty = 0; ty < 7; ty++) {
        int yy = y + 3 * (ty - 3); if (yy < 0 || yy >= 32) continue;
        for (int tx = 0; tx < 7; tx++) {
            int xv = xx + 3 * (tx - 3); if (xv < 0 || xv >= 32) continue;
            const float* col = ib + yy * 32 + xv;
            float cv[32];
            #pragma unroll
            for (int zz = 0; zz < 32; zz++) cv[zz] = col[(size_t)zz * 1024];
            #pragma unroll
            for (int tz = 0; tz < 7; tz++) {
                float wv = wc[(tz * 7 + ty) * 7 + tx];
                const int o = 3 * (tz - 3);
                #pragma unroll
                for (int z = 0; z < 32; z++) {
                    int zz = z + o;
                    if (zz >= 0 && zz < 32) acc[z] += wv * cv[zz];
                }
            }
        }
    }
    float* ob = out + ((size_t)b * CCH + c) * SVOL + y * 32 + xx;
    #pragma unroll
    for (int z = 0; z < 32; z++) ob[(size_t)z * 1024] = acc[z];
}

// ---------------- transpose [C][S] -> [S][C] fp16 records ----------------
__global__ __launch_bounds__(256)
void transpose_h_kernel(const float* __restrict__ a1, __half* __restrict__ a1h) {
    __shared__ float tile[CCH * 65];
    int tid = threadIdx.x;
    int b = blockIdx.y;
    int s0 = blockIdx.x * 64;
    const float* ib = a1 + (size_t)b * CCH * SVOL + s0;
    for (int i = tid; i < CCH * 64; i += 256) {
        int c = i >> 6, p = i & 63;
        tile[c * 65 + p] = ib[(size_t)c * SVOL + p];
    }
    __syncthreads();
    __half* ob = a1h + ((size_t)b * SVOL + s0) * CCH;
    for (int i = tid; i < 64 * CCH; i += 256) {
        int p = i / CCH, c = i % CCH;
        ob[i] = __float2half(tile[c * 65 + p]);
    }
}

// ---- offset conv 3x3x3: 48->81, ci-split 2 x out-split 3, scalar weights, atomic, NO bias ----
__global__ __launch_bounds__(256, 4)
void offconv_kernel(const float* __restrict__ a1, const float* __restrict__ wt,
                    float* __restrict__ off) {
    int tid = threadIdx.x;
    int go = blockIdx.y % 3;
    int gc = blockIdx.y / 3;
    int b = blockIdx.z;
    int s = blockIdx.x * 256 + tid;
    int z = s >> 10, y = (s >> 5) & 31, xx = s & 31;
    const float* ib = a1 + ((size_t)b * CCH + gc * 24) * SVOL;
    float acc[27];
    #pragma unroll
    for (int o = 0; o < 27; o++) acc[o] = 0.f;
    for (int tap = 0; tap < 27; tap++) {
        int dz = tap / 9 - 1, dy = (tap / 3) % 3 - 1, dx = tap % 3 - 1;
        int zz = z + dz, yy = y + dy, xv = xx + dx;
        bool ok = (zz >= 0 && zz < 32 && yy >= 0 && yy < 32 && xv >= 0 && xv < 32);
        if (ok) {
            int si = (zz * 32 + yy) * 32 + xv;
            for (int cis = 0; cis < 24; cis++) {
                float v = ib[(size_t)cis * SVOL + si];
                const float* wr = wt + (size_t)(tap * CCH + gc * 24 + cis) * 81 + go * 27;
                #pragma unroll
                for (int o = 0; o < 27; o++) acc[o] += wr[o] * v;
            }
        }
    }
    float* obuf = off + (size_t)b * 81 * SVOL + (size_t)(go * 27) * SVOL + s;
    #pragma unroll
    for (int o = 0; o < 27; o++) atomicAdd(&obuf[(size_t)o * SVOL], acc[o]);
}

// ---- deformable conv 3x3x3: ci-split 3 (16 ch), packed fp16 interp + v_dot2_f32_f16 matmul ----
// a1h layout [b][s][48] half; wt half2 layout [(k*24+cp)*48+o]; off bias-less.
struct h8v { half2_t a, b, c, d; };   // 16 bytes = 8 halves

__global__ __launch_bounds__(256, 4)
void deform_kernel(const __half* __restrict__ a1h, const float* __restrict__ off,
                   const float* __restrict__ off_b,
                   const __half2* __restrict__ wt, float* __restrict__ out) {
    int tid = threadIdx.x;
    int gc = blockIdx.y;            // ci group 0..2 (16 ch = 8 pairs each)
    int b = blockIdx.z;
    int s = blockIdx.x * 256 + tid;
    int z = s >> 10, y = (s >> 5) & 31, xx = s & 31;
    const __half* abase = a1h + (size_t)b * SVOL * CCH + gc * 16;
    const float* ob = off + (size_t)b * 81 * SVOL + s;
    float acc[CCH];
    #pragma unroll
    for (int o = 0; o < CCH; o++) acc[o] = 0.f;
    for (int k = 0; k < 27; k++) {
        int kd = k / 9 - 1, kh = (k / 3) % 3 - 1, kw = k % 3 - 1;
        float zf = (float)(z + kd) + ob[(size_t)(k * 3 + 0) * SVOL] + off_b[k * 3 + 0];
        float yf = (float)(y + kh) + ob[(size_t)(k * 3 + 1) * SVOL] + off_b[k * 3 + 1];
        float xf = (float)(xx + kw) + ob[(size_t)(k * 3 + 2) * SVOL] + off_b[k * 3 + 2];
        float z0 = floorf(zf), y0 = floorf(yf), x0 = floorf(xf);
        float tz = zf - z0, ty = yf - y0, tx = xf - x0;
        int iz0 = (int)z0, iy0 = (int)y0, ix0 = (int)x0;
        half2_t val2[8];
        #pragma unroll
        for (int j = 0; j < 8; j++) val2[j] = (half2_t)(_Float16)0;
        #pragma unroll
        for (int corner = 0; corner < 8; corner++) {
            int dz = corner >> 2, dy = (corner >> 1) & 1, dx = corner & 1;
            int zi = iz0 + dz, yi = iy0 + dy, xi = ix0 + dx;
            bool valid = (zi >= 0 && zi < 32 && yi >= 0 && yi < 32 && xi >= 0 && xi < 32);
            float wgt = (dz ? tz : 1.f - tz) * (dy ? ty : 1.f - ty) * (dx ? tx : 1.f - tx);
            float cwv = valid ? wgt : 0.f;
            _Float16 cwh = (_Float16)cwv;
            half2_t cw2 = { cwh, cwh };
            int zc = min(max(zi, 0), 31), yc = min(max(yi, 0), 31), xc = min(max(xi, 0), 31);
            int cidx = (zc * 32 + yc) * 32 + xc;
            const h8v* pv = (const h8v*)(abase + (size_t)cidx * CCH);
            h8v q0 = pv[0], q1 = pv[1];
            val2[0] += cw2 * q0.a;  val2[1] += cw2 * q0.b;
            val2[2] += cw2 * q0.c;  val2[3] += cw2 * q0.d;
            val2[4] += cw2 * q1.a;  val2[5] += cw2 * q1.b;
            val2[6] += cw2 * q1.c;  val2[7] += cw2 * q1.d;
        }
        #pragma unroll
        for (int cpl = 0; cpl < 8; cpl++) {
            half2_t v2 = val2[cpl];
            const half2_t* wr = (const half2_t*)(wt + ((size_t)k * 24 + gc * 8 + cpl) * CCH);  // uniform
            #pragma unroll
            for (int o = 0; o < CCH; o++) acc[o] = dot2f(v2, wr[o], acc[o]);
        }
    }
    float* op = out + (size_t)b * CCH * SVOL + s;
    #pragma unroll
    for (int o = 0; o < CCH; o++) atomicAdd(&op[(size_t)o * SVOL], acc[o]);
}

// ---- gate1: a2 = (c1 . dc + cb) * u   (4 groups x 12), scalar weights ----
__global__ __launch_bounds__(256, 4)
void gate1_kernel(const float* __restrict__ dc, const float* __restrict__ u,
                  const float* __restrict__ wt, const float* __restrict__ cb,
                  float* __restrict__ a2buf) {
    int tid = threadIdx.x;
    int g = blockIdx.y, b = blockIdx.z;
    int s = blockIdx.x * 256 + tid;
    size_t base = (size_t)b * CCH * SVOL + s;
    float acc[12];
    #pragma unroll
    for (int o = 0; o < 12; o++) acc[o] = cb[g * 12 + o];
    for (int ci = 0; ci < CCH; ci++) {
        float v = dc[base + (size_t)ci * SVOL];
        const float* wr = wt + ci * CCH + g * 12;
        #pragma unroll
        for (int o = 0; o < 12; o++) acc[o] += wr[o] * v;
    }
    #pragma unroll
    for (int o = 0; o < 12; o++) {
        size_t oo = base + (size_t)(g * 12 + o) * SVOL;
        a2buf[oo] = acc[o] * u[oo];
    }
}

// ---- gate2: skip = x + gamma*(p2 . a2 + p2b + xn)  (4 groups x 12), scalar weights ----
__global__ __launch_bounds__(256, 4)
void gate2_kernel(const float* __restrict__ a2buf, const float* __restrict__ xn,
                  const float* __restrict__ x,
                  const float* __restrict__ wt, const float* __restrict__ p2b,
                  const float* __restrict__ gamma, float* __restrict__ skip) {
    int tid = threadIdx.x;
    int g = blockIdx.y, b = blockIdx.z;
    int s = blockIdx.x * 256 + tid;
    size_t base = (size_t)b * CCH * SVOL + s;
    float acc[12];
    #pragma unroll
    for (int o = 0; o < 12; o++) acc[o] = p2b[g * 12 + o];
    for (int ci = 0; ci < CCH; ci++) {
        float v = a2buf[base + (size_t)ci * SVOL];
        const float* wr = wt + ci * CCH + g * 12;
        #pragma unroll
        for (int o = 0; o < 12; o++) acc[o] += wr[o] * v;
    }
    #pragma unroll
    for (int o = 0; o < 12; o++) {
        int oc = g * 12 + o;
        float vv = acc[o] + xn[base + (size_t)oc * SVOL];
        skip[base + (size_t)oc * SVOL] = x[base + (size_t)oc * SVOL] + gamma[oc] * vv;
    }
}

// ---- u1: 3x3x3 conv + BN1 + LeakyReLU (4 groups x 12), scalar weights [tap][ci][48] ----
__global__ __launch_bounds__(256, 4)
void u1_kernel(const float* __restrict__ in, const float* __restrict__ wt,
               const float* __restrict__ bs, const float* __restrict__ bb,
               const float* __restrict__ bm, const float* __restrict__ bv,
               float* __restrict__ out) {
    int tid = threadIdx.x;
    int g = blockIdx.y, b = blockIdx.z;
    int s = blockIdx.x * 256 + tid;
    int z = s >> 10, y = (s >> 5) & 31, xx = s & 31;
    const float* ib = in + (size_t)b * CCH * SVOL;
    float acc[12];
    #pragma unroll
    for (int o = 0; o < 12; o++) acc[o] = 0.f;
    for (int tap = 0; tap < 27; tap++) {
        int dz = tap / 9 - 1, dy = (tap / 3) % 3 - 1, dx = tap % 3 - 1;
        int zz = z + dz, yy = y + dy, xv = xx + dx;
        bool ok = (zz >= 0 && zz < 32 && yy >= 0 && yy < 32 && xv >= 0 && xv < 32);
        if (ok) {
            int si = (zz * 32 + yy) * 32 + xv;
            for (int ci = 0; ci < CCH; ci++) {
                float v = ib[(size_t)ci * SVOL + si];
                const float* wr = wt + (size_t)(tap * CCH + ci) * CCH + g * 12;
                #pragma unroll
                for (int o = 0; o < 12; o++) acc[o] += wr[o] * v;
            }
        }
    }
    float* op = out + (size_t)b * CCH * SVOL + (size_t)(g * 12) * SVOL + s;
    #pragma unroll
    for (int o = 0; o < 12; o++) {
        int oc = g * 12 + o;
        float inv = rsqrtf(bv[oc] + 1e-5f);
        float h = (acc[o] - bm[oc]) * (bs[oc] * inv) + bb[oc];
        op[(size_t)o * SVOL] = h >= 0.f ? h : 0.01f * h;
    }
}

// ---- u2_bn: 3x3x3 conv + BN2 + (+skip) + LeakyReLU -> attn (4 groups x 12), scalar weights ----
__global__ __launch_bounds__(256, 4)
void u2_bn_kernel(const float* __restrict__ h1, const float* __restrict__ skip,
                  const float* __restrict__ wt,
                  const float* __restrict__ bs, const float* __restrict__ bb,
                  const float* __restrict__ bm, const float* __restrict__ bv,
                  float* __restrict__ attn) {
    int tid = threadIdx.x;
    int g = blockIdx.y, b = blockIdx.z;
    int s = blockIdx.x * 256 + tid;
    int z = s >> 10, y = (s >> 5) & 31, xx = s & 31;
    const float* ib = h1 + (size_t)b * CCH * SVOL;
    float acc[12];
    #pragma unroll
    for (int o = 0; o < 12; o++) acc[o] = 0.f;
    for (int tap = 0; tap < 27; tap++) {
        int dz = tap / 9 - 1, dy = (tap / 3) % 3 - 1, dx = tap % 3 - 1;
        int zz = z + dz, yy = y + dy, xv = xx + dx;
        bool ok = (zz >= 0 && zz < 32 && yy >= 0 && yy < 32 && xv >= 0 && xv < 32);
        if (ok) {
            int si = (zz * 32 + yy) * 32 + xv;
            for (int ci = 0; ci < CCH; ci++) {
                float v = ib[(size_t)ci * SVOL + si];
                const float* wr = wt + (size_t)(tap * CCH + ci) * CCH + g * 12;
                #pragma unroll
                for (int o = 0; o < 12; o++) acc[o] += wr[o] * v;
            }
        }
    }
    size_t base = (size_t)b * CCH * SVOL + s;
    #pragma unroll
    for (int o = 0; o < 12; o++) {
        int oc = g * 12 + o;
        float inv = rsqrtf(bv[oc] + 1e-5f);
        float h = (acc[o] - bm[oc]) * (bs[oc] * inv) + bb[oc];
        float a = h + skip[base + (size_t)oc * SVOL];
        attn[base + (size_t)oc * SVOL] = a >= 0.f ? a : 0.01f * a;
    }
}

// ---- pr_final: out = skip + pr(attn)  (4 groups x 12), scalar weights ----
__global__ __launch_bounds__(256, 4)
void pr_final_kernel(const float* __restrict__ attn, const float* __restrict__ skip,
                     const float* __restrict__ wt, const float* __restrict__ prb,
                     float* __restrict__ out) {
    int tid = threadIdx.x;
    int g = blockIdx.y, b = blockIdx.z;
    int s = blockIdx.x * 256 + tid;
    size_t base = (size_t)b * CCH * SVOL + s;
    float acc[12];
    #pragma unroll
    for (int o = 0; o < 12; o++) acc[o] = prb[g * 12 + o];
    for (int ci = 0; ci < CCH; ci++) {
        float v = attn[base + (size_t)ci * SVOL];
        const float* wr = wt + ci * CCH + g * 12;
        #pragma unroll
        for (int o = 0; o < 12; o++) acc[o] += wr[o] * v;
    }
    #pragma unroll
    for (int o = 0; o < 12; o++) {
        int oc = g * 12 + o;
        out[base + (size_t)oc * SVOL] = skip[base + (size_t)oc * SVOL] + acc[o];
    }
}

extern "C" void kernel_launch(void* const* d_in, const int* in_sizes, int n_in,
                              void* d_out, int out_size, void* d_ws, size_t ws_size,
                              hipStream_t stream) {
    (void)in_sizes; (void)n_in; (void)out_size; (void)ws_size;
    const float* x     = (const float*)d_in[0];
    const float* ln_s  = (const float*)d_in[1];
    const float* ln_b  = (const float*)d_in[2];
    const float* gamma = (const float*)d_in[3];
    const float* p1_w  = (const float*)d_in[4];
    const float* p1_b  = (const float*)d_in[5];
    const float* p2_w  = (const float*)d_in[6];
    const float* p2_b  = (const float*)d_in[7];
    const float* c0_w  = (const float*)d_in[8];
    const float* c0_b  = (const float*)d_in[9];
    const float* cs_w  = (const float*)d_in[10];
    const float* cs_b  = (const float*)d_in[11];
    const float* off_w = (const float*)d_in[12];
    const float* off_b = (const float*)d_in[13];
    const float* dc_w  = (const float*)d_in[14];
    const float* dc_b  = (const float*)d_in[15];
    const float* c1_w  = (const float*)d_in[16];
    const float* c1_b  = (const float*)d_in[17];
    const float* u1_w  = (const float*)d_in[18];
    const float* bn1_s = (const float*)d_in[19];
    const float* bn1_b = (const float*)d_in[20];
    const float* bn1_m = (const float*)d_in[21];
    const float* bn1_v = (const float*)d_in[22];
    const float* u2_w  = (const float*)d_in[23];
    const float* bn2_s = (const float*)d_in[24];
    const float* bn2_b = (const float*)d_in[25];
    const float* bn2_m = (const float*)d_in[26];
    const float* bn2_v = (const float*)d_in[27];
    const float* pr_w  = (const float*)d_in[28];
    const float* pr_b  = (const float*)d_in[29];
    float* out = (float*)d_out;

    float* wsf = (float*)d_ws;
    const size_t TS = (size_t)NB * CCH * SVOL;   // 3,145,728 floats
    float* xn   = out;            // d_out doubles as xn (dead before final write)
    float* ubuf = wsf;            // u (gelu out) -> h1 (u1 out)
    float* bufA = wsf + TS;       // dw5 out -> a1h (half, ch-last) -> skip
    float* bufB = wsf + 2 * TS;   // dw7 out (a1) -> deform partials (dc)
    float* offb = wsf + 3 * TS;   // offset partials [B,81,S] -> a2 -> attn
    float* wtb    = wsf + 3 * TS + (size_t)NB * 81 * SVOL;
    float* wt_off = wtb;                    // 27*48*81 = 104976
    float* wt_dcf = wt_off + 104976;        // reused: half2-packed dc weights (31104 h2 = 31104 floats)
    float* wt_u1  = wt_dcf + 62208;
    float* wt_u2  = wt_u1 + 62208;
    float* pt_p1  = wt_u2 + 62208;          // 2304
    float* pt_c1  = pt_p1 + 2304;
    float* pt_p2  = pt_c1 + 2304;
    float* pt_pr  = pt_p2 + 2304;
    float* cb_all = pt_pr + 2304;           // 48
    __half* a1h = (__half*)bufA;            // NB*SVOL*48 halves = 6.3 MB (fits in bufA)
    __half2* wt_dch = (__half2*)wt_dcf;

    dim3 blk(256);
    dim3 gpos(SVOL / 256, NB);
    dim3 g4(SVOL / 256, 4, NB);
    dim3 g6(SVOL / 256, 6, NB);
    dim3 g3d(SVOL / 256, 3, NB);
    dim3 gdwc(1024 / 256, CCH, NB);    // z-column depthwise
    dim3 gtr(SVOL / 64, NB);

    hipLaunchKernelGGL(reshape_tap_kernel, dim3((104976 + 255) / 256), blk, 0, stream, off_w, wt_off, 81, CCH);
    hipLaunchKernelGGL(reshape_dc_h_kernel, dim3((31104 + 255) / 256), blk, 0, stream, dc_w, wt_dch);
    hipLaunchKernelGGL(reshape_tap_kernel, dim3((62208 + 255) / 256),  blk, 0, stream, u1_w,  wt_u1,  CCH, CCH);
    hipLaunchKernelGGL(reshape_tap_kernel, dim3((62208 + 255) / 256),  blk, 0, stream, u2_w,  wt_u2,  CCH, CCH);
    hipLaunchKernelGGL(t1x1_kernel, dim3(9), blk, 0, stream, p1_w, pt_p1);
    hipLaunchKernelGGL(t1x1_kernel, dim3(9), blk, 0, stream, c1_w, pt_c1);
    hipLaunchKernelGGL(t1x1_kernel, dim3(9), blk, 0, stream, p2_w, pt_p2);
    hipLaunchKernelGGL(t1x1_kernel, dim3(9), blk, 0, stream, pr_w, pt_pr);
    hipLaunchKernelGGL(cb_kernel, dim3(1), dim3(64), 0, stream, c1_w, c1_b, dc_b, cb_all);

    hipLaunchKernelGGL(ln_kernel,          gpos, blk, 0, stream, x, ln_s, ln_b, xn);
    hipLaunchKernelGGL(p1_gelu_kernel,     g4,   blk, 0, stream, xn, pt_p1, p1_b, ubuf);
    hipLaunchKernelGGL(dw5_kernel,         gdwc, blk, 0, stream, ubuf, c0_w, c0_b, bufA);
    hipLaunchKernelGGL(dw7_kernel,         gdwc, blk, 0, stream, bufA, cs_w, cs_b, bufB);
    hipLaunchKernelGGL(transpose_h_kernel, gtr,  blk, 0, stream, bufB, a1h);   // a1 -> a1h (fp16)
    hipMemsetAsync(offb, 0, (size_t)NB * 81 * SVOL * sizeof(float), stream);
    hipLaunchKernelGGL(offconv_kernel,     g6,   blk, 0, stream, bufB, wt_off, offb);
    hipMemsetAsync(bufB, 0, TS * sizeof(float), stream);
    hipLaunchKernelGGL(deform_kernel,      g3d,  blk, 0, stream, a1h, offb, off_b, wt_dch, bufB);
    hipLaunchKernelGGL(gate1_kernel,       g4,   blk, 0, stream, bufB, ubuf, pt_c1, cb_all, offb);
    hipLaunchKernelGGL(gate2_kernel,       g4,   blk, 0, stream, offb, xn, x, pt_p2, p2_b, gamma, bufA);
    hipLaunchKernelGGL(u1_kernel,          g4,   blk, 0, stream, bufA, wt_u1,
                       bn1_s, bn1_b, bn1_m, bn1_v, ubuf);
    hipLaunchKernelGGL(u2_bn_kernel,       g4,   blk, 0, stream, ubuf, bufA, wt_u2,
                       bn2_s, bn2_b, bn2_m, bn2_v, offb);
    hipLaunchKernelGGL(pr_final_kernel,    g4,   blk, 0, stream, offb, bufA, pt_pr, pr_b, out);
}

// Round 14
// 659.464 us; speedup vs baseline: 2.4663x; 1.1396x over previous
//
#include <hip/hip_runtime.h>
#include <hip/hip_fp16.h>
#include <math.h>

#define CCH 48
#define SDIM 32
#define SVOL (SDIM*SDIM*SDIM)
#define NB 2

typedef _Float16 half2_t __attribute__((ext_vector_type(2)));

static __device__ __forceinline__ float dot2f(half2_t a, half2_t b, float c) {
#if __has_builtin(__builtin_amdgcn_fdot2)
    return __builtin_amdgcn_fdot2(a, b, c, false);
#else
    return c + (float)a[0] * (float)b[0] + (float)a[1] * (float)b[1];
#endif
}

// ======== one-off weight reshape kernels ========

// generic fp16 channel-pair reshape: w[o][ci][27] (ci=48) -> wt[(k*24+cp)*NO+o] = (w[o][2cp][k], w[o][2cp+1][k])
__global__ __launch_bounds__(256)
void reshape_pair_kernel(const float* __restrict__ w, half2_t* __restrict__ wt, int NO) {
    int i = blockIdx.x * 256 + threadIdx.x;
    int total = 27 * 24 * NO;
    if (i < total) {
        int o = i % NO; int rem = i / NO; int cp = rem % 24; int k = rem / 24;
        float w0 = w[((size_t)o * CCH + 2 * cp) * 27 + k];
        float w1 = w[((size_t)o * CCH + 2 * cp + 1) * 27 + k];
        wt[i] = half2_t{ (_Float16)w0, (_Float16)w1 };
    }
}

__global__ __launch_bounds__(256)
void t1x1_kernel(const float* __restrict__ w, float* __restrict__ wt) {
    int i = blockIdx.x * 256 + threadIdx.x;
    if (i < CCH * CCH) { int ci = i / CCH, o = i % CCH; wt[i] = w[o * CCH + ci]; }
}

__global__ __launch_bounds__(64)
void cb_kernel(const float* __restrict__ c1w, const float* __restrict__ c1b,
               const float* __restrict__ dcb, float* __restrict__ cb) {
    int o = threadIdx.x;
    if (o < CCH) {
        float v = c1b[o];
        for (int ci = 0; ci < CCH; ci++) v += c1w[o * CCH + ci] * dcb[ci];
        cb[o] = v;
    }
}

// ---- pack fp32 [48][S] -> half2 pairs [24][S] ----
__global__ __launch_bounds__(256)
void pack_pairs_kernel(const float* __restrict__ in, half2_t* __restrict__ out) {
    int tid = threadIdx.x;
    int cp = blockIdx.y, b = blockIdx.z;
    int s = blockIdx.x * 256 + tid;
    const float* i0 = in + ((size_t)b * CCH + 2 * cp) * SVOL;
    out[((size_t)b * 24 + cp) * SVOL + s] =
        half2_t{ (_Float16)i0[s], (_Float16)i0[SVOL + s] };
}

// ---------------- LayerNorm over C ----------------
__global__ __launch_bounds__(256)
void ln_kernel(const float* __restrict__ x, const float* __restrict__ ln_s,
               const float* __restrict__ ln_b, float* __restrict__ xn) {
    int s = blockIdx.x * 256 + threadIdx.x;
    int b = blockIdx.y;
    const float* xb = x + (size_t)b * CCH * SVOL + s;
    float v[CCH];
    float mu = 0.f;
    #pragma unroll
    for (int c = 0; c < CCH; c++) { v[c] = xb[c * SVOL]; mu += v[c]; }
    mu *= (1.0f / CCH);
    float var = 0.f;
    #pragma unroll
    for (int c = 0; c < CCH; c++) { float d = v[c] - mu; var += d * d; }
    var *= (1.0f / CCH);
    float inv = rsqrtf(var + 1e-5f);
    float* o = xn + (size_t)b * CCH * SVOL + s;
    #pragma unroll
    for (int c = 0; c < CCH; c++) o[c * SVOL] = (v[c] - mu) * inv * ln_s[c] + ln_b[c];
}

// ---------------- 1x1x1 conv + exact GELU (4 groups x 12), scalar weights ----------------
__global__ __launch_bounds__(256, 4)
void p1_gelu_kernel(const float* __restrict__ xn, const float* __restrict__ wt,
                    const float* __restrict__ bias, float* __restrict__ u) {
    int tid = threadIdx.x;
    int g = blockIdx.y, b = blockIdx.z;
    int s = blockIdx.x * 256 + tid;
    const float* xb = xn + (size_t)b * CCH * SVOL + s;
    float acc[12];
    #pragma unroll
    for (int o = 0; o < 12; o++) acc[o] = bias[g * 12 + o];
    for (int c = 0; c < CCH; c++) {
        float v = xb[c * SVOL];
        const float* wr = wt + c * CCH + g * 12;
        #pragma unroll
        for (int o = 0; o < 12; o++) acc[o] += wr[o] * v;
    }
    float* ub = u + (size_t)b * CCH * SVOL + s + (size_t)(g * 12) * SVOL;
    #pragma unroll
    for (int o = 0; o < 12; o++) {
        float a = acc[o];
        ub[o * SVOL] = 0.5f * a * (1.0f + erff(a * 0.70710678118654752f));
    }
}

// ---- depthwise 5x5x5 pad 2: z-column register blocking ----
__global__ __launch_bounds__(256, 2)
void dw5_kernel(const float* __restrict__ in, const float* __restrict__ w,
                const float* __restrict__ bias, float* __restrict__ out) {
    int tid = threadIdx.x;
    int c = blockIdx.y, b = blockIdx.z;
    const float* wc = w + c * 125;
    int yx = blockIdx.x * 256 + tid;
    int y = yx >> 5, xx = yx & 31;
    const float* ib = in + ((size_t)b * CCH + c) * SVOL;
    float acc[32];
    float bv = bias[c];
    #pragma unroll
    for (int z = 0; z < 32; z++) acc[z] = bv;
    for (int ty = 0; ty < 5; ty++) {
        int yy = y + ty - 2; if (yy < 0 || yy >= 32) continue;
        for (int tx = 0; tx < 5; tx++) {
            int xv = xx + tx - 2; if (xv < 0 || xv >= 32) continue;
            const float* col = ib + yy * 32 + xv;
            float cv[32];
            #pragma unroll
            for (int zz = 0; zz < 32; zz++) cv[zz] = col[(size_t)zz * 1024];
            #pragma unroll
            for (int tz = 0; tz < 5; tz++) {
                float wv = wc[(tz * 5 + ty) * 5 + tx];
                const int o = tz - 2;
                #pragma unroll
                for (int z = 0; z < 32; z++) {
                    int zz = z + o;
                    if (zz >= 0 && zz < 32) acc[z] += wv * cv[zz];
                }
            }
        }
    }
    float* ob = out + ((size_t)b * CCH + c) * SVOL + y * 32 + xx;
    #pragma unroll
    for (int z = 0; z < 32; z++) ob[(size_t)z * 1024] = acc[z];
}

// ---- depthwise 7x7x7 dil 3 pad 9: z-column register blocking ----
__global__ __launch_bounds__(256, 2)
void dw7_kernel(const float* __restrict__ in, const float* __restrict__ w,
                const float* __restrict__ bias, float* __restrict__ out) {
    int tid = threadIdx.x;
    int c = blockIdx.y, b = blockIdx.z;
    const float* wc = w + c * 343;
    int yx = blockIdx.x * 256 + tid;
    int y = yx >> 5, xx = yx & 31;
    const float* ib = in + ((size_t)b * CCH + c) * SVOL;
    float acc[32];
    float bv = bias[c];
    #pragma unroll
    for (int z = 0; z < 32; z++) acc[z] = bv;
    for (int ty = 0; ty < 7; ty++) {
        int yy = y + 3 * (ty - 3); if (yy < 0 || yy >= 32) continue;
        for (int tx = 0; tx < 7; tx++) {
            int xv = xx + 3 * (tx - 3); if (xv < 0 || xv >= 32) continue;
            const float* col = ib + yy * 32 + xv;
            float cv[32];
            #pragma unroll
            for (int zz = 0; zz < 32; zz++) cv[zz] = col[(size_t)zz * 1024];
            #pragma unroll
            for (int tz = 0; tz < 7; tz++) {
                float wv = wc[(tz * 7 + ty) * 7 + tx];
                const int o = 3 * (tz - 3);
                #pragma unroll
                for (int z = 0; z < 32; z++) {
                    int zz = z + o;
                    if (zz >= 0 && zz < 32) acc[z] += wv * cv[zz];
                }
            }
        }
    }
    float* ob = out + ((size_t)b * CCH + c) * SVOL + y * 32 + xx;
    #pragma unroll
    for (int z = 0; z < 32; z++) ob[(size_t)z * 1024] = acc[z];
}

// ---------------- transpose [C][S] -> [S][C] fp16 records (deform input) ----------------
__global__ __launch_bounds__(256)
void transpose_h_kernel(const float* __restrict__ a1, __half* __restrict__ a1h) {
    __shared__ float tile[CCH * 65];
    int tid = threadIdx.x;
    int b = blockIdx.y;
    int s0 = blockIdx.x * 64;
    const float* ib = a1 + (size_t)b * CCH * SVOL + s0;
    for (int i = tid; i < CCH * 64; i += 256) {
        int c = i >> 6, p = i & 63;
        tile[c * 65 + p] = ib[(size_t)c * SVOL + p];
    }
    __syncthreads();
    __half* ob = a1h + ((size_t)b * SVOL + s0) * CCH;
    for (int i = tid; i < 64 * CCH; i += 256) {
        int p = i / CCH, c = i % CCH;
        ob[i] = __float2half(tile[c * 65 + p]);
    }
}

// ---- offset conv 3x3x3: 48->81, pair-split 2 x out-split 3, fp16 dot2, atomic, NO bias ----
// a1p half2 [b][24][S]; wt half2 [(tap*24+cp)*81+o]
__global__ __launch_bounds__(256, 4)
void offconv_kernel(const half2_t* __restrict__ a1p, const half2_t* __restrict__ wt,
                    float* __restrict__ off) {
    int tid = threadIdx.x;
    int go = blockIdx.y % 3;
    int gc = blockIdx.y / 3;        // 0..1 (12 pairs each)
    int b = blockIdx.z;
    int s = blockIdx.x * 256 + tid;
    int z = s >> 10, y = (s >> 5) & 31, xx = s & 31;
    const half2_t* ib = a1p + ((size_t)b * 24 + gc * 12) * SVOL;
    float acc[27];
    #pragma unroll
    for (int o = 0; o < 27; o++) acc[o] = 0.f;
    for (int tap = 0; tap < 27; tap++) {
        int dz = tap / 9 - 1, dy = (tap / 3) % 3 - 1, dx = tap % 3 - 1;
        int zz = z + dz, yy = y + dy, xv = xx + dx;
        bool ok = (zz >= 0 && zz < 32 && yy >= 0 && yy < 32 && xv >= 0 && xv < 32);
        if (ok) {
            int si = (zz * 32 + yy) * 32 + xv;
            for (int cp = 0; cp < 12; cp++) {
                half2_t v2 = ib[(size_t)cp * SVOL + si];
                const half2_t* wr = wt + ((size_t)tap * 24 + gc * 12 + cp) * 81 + go * 27;  // uniform
                #pragma unroll
                for (int o = 0; o < 27; o++) acc[o] = dot2f(v2, wr[o], acc[o]);
            }
        }
    }
    float* obuf = off + (size_t)b * 81 * SVOL + (size_t)(go * 27) * SVOL + s;
    #pragma unroll
    for (int o = 0; o < 27; o++) atomicAdd(&obuf[(size_t)o * SVOL], acc[o]);
}

// ---- deformable conv 3x3x3: ci-split 3 (16 ch), packed fp16 interp + dot2 matmul ----
struct h8v { half2_t a, b, c, d; };   // 16 bytes = 8 halves

__global__ __launch_bounds__(256, 4)
void deform_kernel(const __half* __restrict__ a1h, const float* __restrict__ off,
                   const float* __restrict__ off_b,
                   const half2_t* __restrict__ wt, float* __restrict__ out) {
    int tid = threadIdx.x;
    int gc = blockIdx.y;            // ci group 0..2 (16 ch = 8 pairs each)
    int b = blockIdx.z;
    int s = blockIdx.x * 256 + tid;
    int z = s >> 10, y = (s >> 5) & 31, xx = s & 31;
    const __half* abase = a1h + (size_t)b * SVOL * CCH + gc * 16;
    const float* ob = off + (size_t)b * 81 * SVOL + s;
    float acc[CCH];
    #pragma unroll
    for (int o = 0; o < CCH; o++) acc[o] = 0.f;
    for (int k = 0; k < 27; k++) {
        int kd = k / 9 - 1, kh = (k / 3) % 3 - 1, kw = k % 3 - 1;
        float zf = (float)(z + kd) + ob[(size_t)(k * 3 + 0) * SVOL] + off_b[k * 3 + 0];
        float yf = (float)(y + kh) + ob[(size_t)(k * 3 + 1) * SVOL] + off_b[k * 3 + 1];
        float xf = (float)(xx + kw) + ob[(size_t)(k * 3 + 2) * SVOL] + off_b[k * 3 + 2];
        float z0 = floorf(zf), y0 = floorf(yf), x0 = floorf(xf);
        float tz = zf - z0, ty = yf - y0, tx = xf - x0;
        int iz0 = (int)z0, iy0 = (int)y0, ix0 = (int)x0;
        half2_t val2[8];
        #pragma unroll
        for (int j = 0; j < 8; j++) val2[j] = (half2_t)(_Float16)0;
        #pragma unroll
        for (int corner = 0; corner < 8; corner++) {
            int dz = corner >> 2, dy = (corner >> 1) & 1, dx = corner & 1;
            int zi = iz0 + dz, yi = iy0 + dy, xi = ix0 + dx;
            bool valid = (zi >= 0 && zi < 32 && yi >= 0 && yi < 32 && xi >= 0 && xi < 32);
            float wgt = (dz ? tz : 1.f - tz) * (dy ? ty : 1.f - ty) * (dx ? tx : 1.f - tx);
            float cwv = valid ? wgt : 0.f;
            _Float16 cwh = (_Float16)cwv;
            half2_t cw2 = { cwh, cwh };
            int zc = min(max(zi, 0), 31), yc = min(max(yi, 0), 31), xc = min(max(xi, 0), 31);
            int cidx = (zc * 32 + yc) * 32 + xc;
            const h8v* pv = (const h8v*)(abase + (size_t)cidx * CCH);
            h8v q0 = pv[0], q1 = pv[1];
            val2[0] += cw2 * q0.a;  val2[1] += cw2 * q0.b;
            val2[2] += cw2 * q0.c;  val2[3] += cw2 * q0.d;
            val2[4] += cw2 * q1.a;  val2[5] += cw2 * q1.b;
            val2[6] += cw2 * q1.c;  val2[7] += cw2 * q1.d;
        }
        #pragma unroll
        for (int cpl = 0; cpl < 8; cpl++) {
            half2_t v2 = val2[cpl];
            const half2_t* wr = wt + ((size_t)k * 24 + gc * 8 + cpl) * CCH;  // uniform
            #pragma unroll
            for (int o = 0; o < CCH; o++) acc[o] = dot2f(v2, wr[o], acc[o]);
        }
    }
    float* op = out + (size_t)b * CCH * SVOL + s;
    #pragma unroll
    for (int o = 0; o < CCH; o++) atomicAdd(&op[(size_t)o * SVOL], acc[o]);
}

// ---- gate1: a2 = (c1 . dc + cb) * u   (4 groups x 12), scalar weights ----
__global__ __launch_bounds__(256, 4)
void gate1_kernel(const float* __restrict__ dc, const float* __restrict__ u,
                  const float* __restrict__ wt, const float* __restrict__ cb,
                  float* __restrict__ a2buf) {
    int tid = threadIdx.x;
    int g = blockIdx.y, b = blockIdx.z;
    int s = blockIdx.x * 256 + tid;
    size_t base = (size_t)b * CCH * SVOL + s;
    float acc[12];
    #pragma unroll
    for (int o = 0; o < 12; o++) acc[o] = cb[g * 12 + o];
    for (int ci = 0; ci < CCH; ci++) {
        float v = dc[base + (size_t)ci * SVOL];
        const float* wr = wt + ci * CCH + g * 12;
        #pragma unroll
        for (int o = 0; o < 12; o++) acc[o] += wr[o] * v;
    }
    #pragma unroll
    for (int o = 0; o < 12; o++) {
        size_t oo = base + (size_t)(g * 12 + o) * SVOL;
        a2buf[oo] = acc[o] * u[oo];
    }
}

// ---- gate2: skip = x + gamma*(p2 . a2 + p2b + xn); also writes packed fp16 skip ----
__global__ __launch_bounds__(256, 4)
void gate2_kernel(const float* __restrict__ a2buf, const float* __restrict__ xn,
                  const float* __restrict__ x,
                  const float* __restrict__ wt, const float* __restrict__ p2b,
                  const float* __restrict__ gamma, float* __restrict__ skip,
                  half2_t* __restrict__ skp) {
    int tid = threadIdx.x;
    int g = blockIdx.y, b = blockIdx.z;
    int s = blockIdx.x * 256 + tid;
    size_t base = (size_t)b * CCH * SVOL + s;
    float acc[12];
    #pragma unroll
    for (int o = 0; o < 12; o++) acc[o] = p2b[g * 12 + o];
    for (int ci = 0; ci < CCH; ci++) {
        float v = a2buf[base + (size_t)ci * SVOL];
        const float* wr = wt + ci * CCH + g * 12;
        #pragma unroll
        for (int o = 0; o < 12; o++) acc[o] += wr[o] * v;
    }
    float sv[12];
    #pragma unroll
    for (int o = 0; o < 12; o++) {
        int oc = g * 12 + o;
        float vv = acc[o] + xn[base + (size_t)oc * SVOL];
        sv[o] = x[base + (size_t)oc * SVOL] + gamma[oc] * vv;
        skip[base + (size_t)oc * SVOL] = sv[o];
    }
    half2_t* sp = skp + ((size_t)b * 24 + g * 6) * SVOL + s;
    #pragma unroll
    for (int j = 0; j < 6; j++)
        sp[(size_t)j * SVOL] = half2_t{ (_Float16)sv[2 * j], (_Float16)sv[2 * j + 1] };
}

// ---- u1: 3x3x3 conv + BN1 + LeakyReLU, fp16 dot2; writes packed half2 output ----
__global__ __launch_bounds__(256, 4)
void u1_kernel(const half2_t* __restrict__ skp, const half2_t* __restrict__ wt,
               const float* __restrict__ bs, const float* __restrict__ bb,
               const float* __restrict__ bm, const float* __restrict__ bv,
               half2_t* __restrict__ h1p) {
    int tid = threadIdx.x;
    int g = blockIdx.y, b = blockIdx.z;
    int s = blockIdx.x * 256 + tid;
    int z = s >> 10, y = (s >> 5) & 31, xx = s & 31;
    const half2_t* ib = skp + (size_t)b * 24 * SVOL;
    float acc[12];
    #pragma unroll
    for (int o = 0; o < 12; o++) acc[o] = 0.f;
    for (int tap = 0; tap < 27; tap++) {
        int dz = tap / 9 - 1, dy = (tap / 3) % 3 - 1, dx = tap % 3 - 1;
        int zz = z + dz, yy = y + dy, xv = xx + dx;
        bool ok = (zz >= 0 && zz < 32 && yy >= 0 && yy < 32 && xv >= 0 && xv < 32);
        if (ok) {
            int si = (zz * 32 + yy) * 32 + xv;
            for (int cp = 0; cp < 24; cp++) {
                half2_t v2 = ib[(size_t)cp * SVOL + si];
                const half2_t* wr = wt + ((size_t)tap * 24 + cp) * CCH + g * 12;  // uniform
                #pragma unroll
                for (int o = 0; o < 12; o++) acc[o] = dot2f(v2, wr[o], acc[o]);
            }
        }
    }
    float hv[12];
    #pragma unroll
    for (int o = 0; o < 12; o++) {
        int oc = g * 12 + o;
        float inv = rsqrtf(bv[oc] + 1e-5f);
        float h = (acc[o] - bm[oc]) * (bs[oc] * inv) + bb[oc];
        hv[o] = h >= 0.f ? h : 0.01f * h;
    }
    half2_t* op = h1p + ((size_t)b * 24 + g * 6) * SVOL + s;
    #pragma unroll
    for (int j = 0; j < 6; j++)
        op[(size_t)j * SVOL] = half2_t{ (_Float16)hv[2 * j], (_Float16)hv[2 * j + 1] };
}

// ---- u2_bn: 3x3x3 conv (fp16 dot2) + BN2 + (+skip fp32) + LeakyReLU -> attn fp32 ----
__global__ __launch_bounds__(256, 4)
void u2_bn_kernel(const half2_t* __restrict__ h1p, const float* __restrict__ skip,
                  const half2_t* __restrict__ wt,
                  const float* __restrict__ bs, const float* __restrict__ bb,
                  const float* __restrict__ bm, const float* __restrict__ bv,
                  float* __restrict__ attn) {
    int tid = threadIdx.x;
    int g = blockIdx.y, b = blockIdx.z;
    int s = blockIdx.x * 256 + tid;
    int z = s >> 10, y = (s >> 5) & 31, xx = s & 31;
    const half2_t* ib = h1p + (size_t)b * 24 * SVOL;
    float acc[12];
    #pragma unroll
    for (int o = 0; o < 12; o++) acc[o] = 0.f;
    for (int tap = 0; tap < 27; tap++) {
        int dz = tap / 9 - 1, dy = (tap / 3) % 3 - 1, dx = tap % 3 - 1;
        int zz = z + dz, yy = y + dy, xv = xx + dx;
        bool ok = (zz >= 0 && zz < 32 && yy >= 0 && yy < 32 && xv >= 0 && xv < 32);
        if (ok) {
            int si = (zz * 32 + yy) * 32 + xv;
            for (int cp = 0; cp < 24; cp++) {
                half2_t v2 = ib[(size_t)cp * SVOL + si];
                const half2_t* wr = wt + ((size_t)tap * 24 + cp) * CCH + g * 12;  // uniform
                #pragma unroll
                for (int o = 0; o < 12; o++) acc[o] = dot2f(v2, wr[o], acc[o]);
            }
        }
    }
    size_t base = (size_t)b * CCH * SVOL + s;
    #pragma unroll
    for (int o = 0; o < 12; o++) {
        int oc = g * 12 + o;
        float inv = rsqrtf(bv[oc] + 1e-5f);
        float h = (acc[o] - bm[oc]) * (bs[oc] * inv) + bb[oc];
        float a = h + skip[base + (size_t)oc * SVOL];
        attn[base + (size_t)oc * SVOL] = a >= 0.f ? a : 0.01f * a;
    }
}

// ---- pr_final: out = skip + pr(attn)  (4 groups x 12), scalar weights ----
__global__ __launch_bounds__(256, 4)
void pr_final_kernel(const float* __restrict__ attn, const float* __restrict__ skip,
                     const float* __restrict__ wt, const float* __restrict__ prb,
                     float* __restrict__ out) {
    int tid = threadIdx.x;
    int g = blockIdx.y, b = blockIdx.z;
    int s = blockIdx.x * 256 + tid;
    size_t base = (size_t)b * CCH * SVOL + s;
    float acc[12];
    #pragma unroll
    for (int o = 0; o < 12; o++) acc[o] = prb[g * 12 + o];
    for (int ci = 0; ci < CCH; ci++) {
        float v = attn[base + (size_t)ci * SVOL];
        const float* wr = wt + ci * CCH + g * 12;
        #pragma unroll
        for (int o = 0; o < 12; o++) acc[o] += wr[o] * v;
    }
    #pragma unroll
    for (int o = 0; o < 12; o++) {
        int oc = g * 12 + o;
        out[base + (size_t)oc * SVOL] = skip[base + (size_t)oc * SVOL] + acc[o];
    }
}

extern "C" void kernel_launch(void* const* d_in, const int* in_sizes, int n_in,
                              void* d_out, int out_size, void* d_ws, size_t ws_size,
                              hipStream_t stream) {
    (void)in_sizes; (void)n_in; (void)out_size; (void)ws_size;
    const float* x     = (const float*)d_in[0];
    const float* ln_s  = (const float*)d_in[1];
    const float* ln_b  = (const float*)d_in[2];
    const float* gamma = (const float*)d_in[3];
    const float* p1_w  = (const float*)d_in[4];
    const float* p1_b  = (const float*)d_in[5];
    const float* p2_w  = (const float*)d_in[6];
    const float* p2_b  = (const float*)d_in[7];
    const float* c0_w  = (const float*)d_in[8];
    const float* c0_b  = (const float*)d_in[9];
    const float* cs_w  = (const float*)d_in[10];
    const float* cs_b  = (const float*)d_in[11];
    const float* off_w = (const float*)d_in[12];
    const float* off_b = (const float*)d_in[13];
    const float* dc_w  = (const float*)d_in[14];
    const float* dc_b  = (const float*)d_in[15];
    const float* c1_w  = (const float*)d_in[16];
    const float* c1_b  = (const float*)d_in[17];
    const float* u1_w  = (const float*)d_in[18];
    const float* bn1_s = (const float*)d_in[19];
    const float* bn1_b = (const float*)d_in[20];
    const float* bn1_m = (const float*)d_in[21];
    const float* bn1_v = (const float*)d_in[22];
    const float* u2_w  = (const float*)d_in[23];
    const float* bn2_s = (const float*)d_in[24];
    const float* bn2_b = (const float*)d_in[25];
    const float* bn2_m = (const float*)d_in[26];
    const float* bn2_v = (const float*)d_in[27];
    const float* pr_w  = (const float*)d_in[28];
    const float* pr_b  = (const float*)d_in[29];
    float* out = (float*)d_out;

    float* wsf = (float*)d_ws;
    const size_t TS = (size_t)NB * CCH * SVOL;   // 3,145,728 floats
    float* xn   = out;            // d_out doubles as xn (dead before final write)
    float* ubuf = wsf;            // u (gelu out) -> [skp | h1p] (half2)
    float* bufA = wsf + TS;       // dw5 out -> [a1h | a1p] -> skip (fp32)
    float* bufB = wsf + 2 * TS;   // dw7 out (a1) -> deform partials (dc)
    float* offb = wsf + 3 * TS;   // offset partials [B,81,S] -> a2 -> attn
    float* wtb    = wsf + 3 * TS + (size_t)NB * 81 * SVOL;
    float* wt_offf = wtb;                   // 52488 half2 = 26244 floats (fits 104976 slot)
    float* wt_dcf  = wt_offf + 104976;      // 31104 half2
    float* wt_u1f  = wt_dcf + 62208;
    float* wt_u2f  = wt_u1f + 62208;
    float* pt_p1  = wt_u2f + 62208;         // 2304
    float* pt_c1  = pt_p1 + 2304;
    float* pt_p2  = pt_c1 + 2304;
    float* pt_pr  = pt_p2 + 2304;
    float* cb_all = pt_pr + 2304;           // 48

    __half*  a1h = (__half*)bufA;                       // 6.3 MB (TS/2 floats)
    half2_t* a1p = (half2_t*)(bufA + TS / 2);           // 6.3 MB
    half2_t* skp = (half2_t*)ubuf;                      // 6.3 MB
    half2_t* h1p = (half2_t*)(ubuf + TS / 2);           // 6.3 MB
    half2_t* wt_offh = (half2_t*)wt_offf;
    half2_t* wt_dch  = (half2_t*)wt_dcf;
    half2_t* wt_u1h  = (half2_t*)wt_u1f;
    half2_t* wt_u2h  = (half2_t*)wt_u2f;

    dim3 blk(256);
    dim3 gpos(SVOL / 256, NB);
    dim3 g4(SVOL / 256, 4, NB);
    dim3 g6(SVOL / 256, 6, NB);
    dim3 g3d(SVOL / 256, 3, NB);
    dim3 gdwc(1024 / 256, CCH, NB);    // z-column depthwise
    dim3 gtr(SVOL / 64, NB);
    dim3 gpk(SVOL / 256, 24, NB);

    hipLaunchKernelGGL(reshape_pair_kernel, dim3((27 * 24 * 81 + 255) / 256), blk, 0, stream, off_w, wt_offh, 81);
    hipLaunchKernelGGL(reshape_pair_kernel, dim3((27 * 24 * 48 + 255) / 256), blk, 0, stream, dc_w,  wt_dch,  48);
    hipLaunchKernelGGL(reshape_pair_kernel, dim3((27 * 24 * 48 + 255) / 256), blk, 0, stream, u1_w,  wt_u1h,  48);
    hipLaunchKernelGGL(reshape_pair_kernel, dim3((27 * 24 * 48 + 255) / 256), blk, 0, stream, u2_w,  wt_u2h,  48);
    hipLaunchKernelGGL(t1x1_kernel, dim3(9), blk, 0, stream, p1_w, pt_p1);
    hipLaunchKernelGGL(t1x1_kernel, dim3(9), blk, 0, stream, c1_w, pt_c1);
    hipLaunchKernelGGL(t1x1_kernel, dim3(9), blk, 0, stream, p2_w, pt_p2);
    hipLaunchKernelGGL(t1x1_kernel, dim3(9), blk, 0, stream, pr_w, pt_pr);
    hipLaunchKernelGGL(cb_kernel, dim3(1), dim3(64), 0, stream, c1_w, c1_b, dc_b, cb_all);

    hipLaunchKernelGGL(ln_kernel,          gpos, blk, 0, stream, x, ln_s, ln_b, xn);
    hipLaunchKernelGGL(p1_gelu_kernel,     g4,   blk, 0, stream, xn, pt_p1, p1_b, ubuf);
    hipLaunchKernelGGL(dw5_kernel,         gdwc, blk, 0, stream, ubuf, c0_w, c0_b, bufA);
    hipLaunchKernelGGL(dw7_kernel,         gdwc, blk, 0, stream, bufA, cs_w, cs_b, bufB);
    hipLaunchKernelGGL(transpose_h_kernel, gtr,  blk, 0, stream, bufB, a1h);   // a1 -> a1h (deform)
    hipLaunchKernelGGL(pack_pairs_kernel,  gpk,  blk, 0, stream, bufB, a1p);   // a1 -> a1p (offconv)
    hipMemsetAsync(offb, 0, (size_t)NB * 81 * SVOL * sizeof(float), stream);
    hipLaunchKernelGGL(offconv_kernel,     g6,   blk, 0, stream, a1p, wt_offh, offb);
    hipMemsetAsync(bufB, 0, TS * sizeof(float), stream);
    hipLaunchKernelGGL(deform_kernel,      g3d,  blk, 0, stream, a1h, offb, off_b, wt_dch, bufB);
    hipLaunchKernelGGL(gate1_kernel,       g4,   blk, 0, stream, bufB, ubuf, pt_c1, cb_all, offb);
    hipLaunchKernelGGL(gate2_kernel,       g4,   blk, 0, stream, offb, xn, x, pt_p2, p2_b, gamma,
                       bufA, skp);
    hipLaunchKernelGGL(u1_kernel,          g4,   blk, 0, stream, skp, wt_u1h,
                       bn1_s, bn1_b, bn1_m, bn1_v, h1p);
    hipLaunchKernelGGL(u2_bn_kernel,       g4,   blk, 0, stream, h1p, bufA, wt_u2h,
                       bn2_s, bn2_b, bn2_m, bn2_v, offb);
    hipLaunchKernelGGL(pr_final_kernel,    g4,   blk, 0, stream, offb, bufA, pt_pr, pr_b, out);
}